// Round 12
// baseline (1248.722 us; speedup 1.0000x reference)
//
#include <hip/hip_runtime.h>

#define NCSR 15
#define MAXP 6
#define MAXT 8
#define MAXG 12
#define NPT 21
#define NWT 37
#define CLOG 14
#define CCHUNK 16384

typedef __attribute__((ext_vector_type(8))) short bfrag;
typedef __attribute__((ext_vector_type(4))) float ffrag;

__device__ __forceinline__ float b2f(unsigned short s) {
  return __uint_as_float(((unsigned int)s) << 16);
}
__device__ __forceinline__ unsigned short f2b(float f) {
  unsigned int u = __float_as_uint(f);
  u = (u + 0x7FFFu + ((u >> 16) & 1u)) >> 16;
  return (unsigned short)u;
}
__device__ __forceinline__ float ldf(const void* p, size_t i, int bf) {
  if (bf) return b2f(((const unsigned short*)p)[i]);
  return ((const float*)p)[i];
}
// load 8 consecutive raw elements (flag dtype) -> packed 8x bf16 in int4
__device__ __forceinline__ int4 ld8(const void* p, size_t i, int bf) {
  if (bf) return *(const int4*)((const unsigned short*)p + i);
  const float* pf = (const float*)p + i;
  float4 f0 = *(const float4*)pf;
  float4 f1 = *(const float4*)(pf + 4);
  int4 v;
  v.x = (int)((unsigned)f2b(f0.x) | ((unsigned)f2b(f0.y) << 16));
  v.y = (int)((unsigned)f2b(f0.z) | ((unsigned)f2b(f0.w) << 16));
  v.z = (int)((unsigned)f2b(f1.x) | ((unsigned)f2b(f1.y) << 16));
  v.w = (int)((unsigned)f2b(f1.z) | ((unsigned)f2b(f1.w) << 16));
  return v;
}

// CSR build WITHOUT global atomics: per-chunk LDS histogram (pass A) ->
// per-(chunk,dst) exclusive bases (pass B, parallel over all dsts) -> fill (pass C)
struct CsrDesc {
  const int* src; const int* dst; int* rowptr; unsigned short* csrc;
  unsigned short* slot16;   // per-edge rank within its chunk (u16, < CCHUNK)
  unsigned int* cnt;        // [nb][n_dst]: counts (pass A) -> exclusive bases (pass B)
  int E, n_dst, nb, pad;
};
struct CsrArgs { CsrDesc d[NCSR]; };
struct COff { int off[16]; };

struct PTask { const void* src; float* dst; int n; int pad; };
struct PArgs { PTask t[NPT]; };

struct WTask { const void* src; unsigned short* dst; int K; int N; int eoff; int pad; };
struct WArgs { WTask t[NWT]; };

struct MPass { const unsigned short* A; const unsigned short* W; const float* bias; int lda; int ldw; int flags; };
struct MTask {
  MPass p[MAXP];
  const unsigned short* R; unsigned short* C;
  int npass, n, K, ldc, relu, pad;
};

struct GTask { const int* rowptr; const unsigned short* csrc; const unsigned short* X; unsigned short* out; int n_dst; int ldx; int mode; int pad; };

struct ETask { const void* A; const unsigned short* W; const float* bias; unsigned short* C; int n, K, ldc, pad; };
struct EArgs { ETask t[3]; };

struct BTask { const void* w; const float* b; unsigned short* out; int n; int pad[3]; };
struct BArgs { BTask t[4]; };

// flat-packed super-launch descriptors: off[i] = first block-x of task i
struct GSup { GTask t[MAXG]; int off[MAXG + 1]; int nt; };
struct MSup { MTask t[MAXT]; int off[MAXT + 1]; int nt; };

__device__ __forceinline__ int find_task(const int* off, int nt, int bx, int& lx) {
  int t = 0;
  while (t + 1 < nt && bx >= off[t + 1]) ++t;
  lx = bx - off[t];
  return t;
}

// ---------------- device bodies ----------------

// pass C: deterministic fill, no atomics
__device__ void fill_body(const CsrDesc& cd, int lx) {
  for (int e = lx * 256 + (int)threadIdx.x; e < cd.E; e += 96 * 256) {
    int d = cd.dst[e];
    int pos = cd.rowptr[d] + (int)cd.cnt[(size_t)(e >> CLOG) * cd.n_dst + d]
              + (int)cd.slot16[e];
    cd.csrc[pos] = (unsigned short)cd.src[e];
  }
}

__device__ void bias_body(const BTask& T, int lx, int bf) {
  const int n8 = T.n >> 3;
  for (int i = lx * 256 + (int)threadIdx.x; i < n8; i += 128 * 256) {
    int base = i << 3;
    int4 v = ld8(T.w, (size_t)base, bf);
    const unsigned short* pv = (const unsigned short*)&v;
    const int cb = base & 127;
    unsigned short o[8];
#pragma unroll
    for (int j = 0; j < 8; ++j) {
      float f = b2f(pv[j]) + T.b[cb + j];
      o[j] = f2b(f > 0.f ? f : 0.f);
    }
    *(int4*)(T.out + base) = *(const int4*)o;
  }
}

// one wave per dst row; lane = one uint = 2 bf16 cols; 4-edge unroll
__device__ void gather_body(const GTask& T, int lx) {
  int w = lx * 4 + ((int)threadIdx.x >> 6);
  if (w >= T.n_dst) return;
  int lane = threadIdx.x & 63;
  int beg = T.rowptr[w], end = T.rowptr[w + 1];
  float a0 = 0.f, a1 = 0.f;
  int j = beg;
  if (T.mode == 0) {
    for (; j + 3 < end; j += 4) {
      unsigned int u0 = ((const unsigned int*)(T.X + (size_t)T.csrc[j] * T.ldx))[lane];
      unsigned int u1 = ((const unsigned int*)(T.X + (size_t)T.csrc[j + 1] * T.ldx))[lane];
      unsigned int u2 = ((const unsigned int*)(T.X + (size_t)T.csrc[j + 2] * T.ldx))[lane];
      unsigned int u3 = ((const unsigned int*)(T.X + (size_t)T.csrc[j + 3] * T.ldx))[lane];
      a0 += __uint_as_float(u0 << 16) + __uint_as_float(u1 << 16)
          + __uint_as_float(u2 << 16) + __uint_as_float(u3 << 16);
      a1 += __uint_as_float(u0 & 0xFFFF0000u) + __uint_as_float(u1 & 0xFFFF0000u)
          + __uint_as_float(u2 & 0xFFFF0000u) + __uint_as_float(u3 & 0xFFFF0000u);
    }
    for (; j < end; ++j) {
      unsigned int u0 = ((const unsigned int*)(T.X + (size_t)T.csrc[j] * T.ldx))[lane];
      a0 += __uint_as_float(u0 << 16);
      a1 += __uint_as_float(u0 & 0xFFFF0000u);
    }
  } else {
    for (; j + 3 < end; j += 4) {
      unsigned int u0 = ((const unsigned int*)(T.X + (size_t)T.csrc[j] * T.ldx))[lane];
      unsigned int u1 = ((const unsigned int*)(T.X + (size_t)T.csrc[j + 1] * T.ldx))[lane];
      unsigned int u2 = ((const unsigned int*)(T.X + (size_t)T.csrc[j + 2] * T.ldx))[lane];
      unsigned int u3 = ((const unsigned int*)(T.X + (size_t)T.csrc[j + 3] * T.ldx))[lane];
      a0 = fmaxf(fmaxf(a0, fmaxf(__uint_as_float(u0 << 16), __uint_as_float(u1 << 16))),
                 fmaxf(__uint_as_float(u2 << 16), __uint_as_float(u3 << 16)));
      a1 = fmaxf(fmaxf(a1, fmaxf(__uint_as_float(u0 & 0xFFFF0000u), __uint_as_float(u1 & 0xFFFF0000u))),
                 fmaxf(__uint_as_float(u2 & 0xFFFF0000u), __uint_as_float(u3 & 0xFFFF0000u)));
    }
    for (; j < end; ++j) {
      unsigned int u0 = ((const unsigned int*)(T.X + (size_t)T.csrc[j] * T.ldx))[lane];
      a0 = fmaxf(a0, __uint_as_float(u0 << 16));
      a1 = fmaxf(a1, __uint_as_float(u0 & 0xFFFF0000u));
    }
  }
  unsigned int* po = (unsigned int*)(T.out + (size_t)w * 128);
  po[lane] = (unsigned int)f2b(a0) | ((unsigned int)f2b(a1) << 16);
}

// MFMA multi-pass GEMM body, 64-row x 128-col tile, BK=64.
// REGISTER DOUBLE-BUFFERED staging: next step's A/W global loads issue while
// current step's MFMA runs -> hides HBM latency (kernels run at low TLP).
__device__ void mg_body(const MTask* T, int lx) {
  const int n = T->n;
  const int row0 = lx * 64;
  if (row0 >= n) return;
  __shared__ __align__(16) unsigned short As[64][72];
  __shared__ __align__(16) unsigned short Ws[128][72];
  const int t = threadIdx.x;
  const int wave = t >> 6, lane = t & 63;
  const int m16 = lane & 15, kq = lane >> 4;
  const int K = T->K;
  const int rbase = t >> 3, col8 = (t & 7) * 8;
  const int npass = T->npass;
  ffrag acc[4][2], accO[4][2];
#pragma unroll
  for (int i = 0; i < 4; ++i)
#pragma unroll
    for (int j = 0; j < 2; ++j) { acc[i][j] = (ffrag)0.f; accO[i][j] = (ffrag)0.f; }
  const int colbase = wave * 32;
  int4 aR[2]; int4 wR[4];
  {  // prefetch step 0 (pass 0, k0 = 0)
    const MPass& p = T->p[0];
#pragma unroll
    for (int j = 0; j < 2; ++j) {
      int row = row0 + rbase + 32 * j;
      int4 v = {0, 0, 0, 0};
      if (row < n) v = *(const int4*)(p.A + (size_t)row * p.lda + col8);
      aR[j] = v;
    }
#pragma unroll
    for (int j = 0; j < 4; ++j)
      wR[j] = *(const int4*)(p.W + (size_t)(rbase + 32 * j) * p.ldw + col8);
  }
  int pip = 0, pk0 = 64;
  if (pk0 >= K) { pk0 = 0; ++pip; }
  for (int ip = 0; ip < npass; ++ip) {
    for (int k0 = 0; k0 < K; k0 += 64) {
      // stage current regs into LDS (prev iteration's trailing barrier protects)
      *(int4*)&As[rbase][col8] = aR[0];
      *(int4*)&As[rbase + 32][col8] = aR[1];
#pragma unroll
      for (int j = 0; j < 4; ++j) *(int4*)&Ws[rbase + 32 * j][col8] = wR[j];
      // issue next step's loads (overlap with barrier + MFMA below)
      if (pip < npass) {
        const MPass& p = T->p[pip];
#pragma unroll
        for (int j = 0; j < 2; ++j) {
          int row = row0 + rbase + 32 * j;
          int4 v = {0, 0, 0, 0};
          if (row < n) v = *(const int4*)(p.A + (size_t)row * p.lda + pk0 + col8);
          aR[j] = v;
        }
#pragma unroll
        for (int j = 0; j < 4; ++j)
          wR[j] = *(const int4*)(p.W + (size_t)(rbase + 32 * j) * p.ldw + pk0 + col8);
        pk0 += 64;
        if (pk0 >= K) { pk0 = 0; ++pip; }
      }
      __syncthreads();
#pragma unroll
      for (int kk = 0; kk < 64; kk += 32) {
        bfrag b0 = *(const bfrag*)&Ws[colbase + m16][kk + kq * 8];
        bfrag b1 = *(const bfrag*)&Ws[colbase + 16 + m16][kk + kq * 8];
#pragma unroll
        for (int rb = 0; rb < 4; ++rb) {
          bfrag a = *(const bfrag*)&As[rb * 16 + m16][kk + kq * 8];
          acc[rb][0] = __builtin_amdgcn_mfma_f32_16x16x32_bf16(a, b0, acc[rb][0], 0, 0, 0);
          acc[rb][1] = __builtin_amdgcn_mfma_f32_16x16x32_bf16(a, b1, acc[rb][1], 0, 0, 0);
        }
      }
      __syncthreads();
    }
    if (T->p[ip].flags & 1) {
      const float* bias = T->p[ip].bias;
      float bv0 = bias ? bias[colbase + m16] : 0.f;
      float bv1 = bias ? bias[colbase + 16 + m16] : 0.f;
#pragma unroll
      for (int rb = 0; rb < 4; ++rb)
#pragma unroll
        for (int cb = 0; cb < 2; ++cb) {
          float bv = cb ? bv1 : bv0;
#pragma unroll
          for (int r = 0; r < 4; ++r) {
            float v = acc[rb][cb][r] + bv;
            if (T->relu) v = v > 0.f ? v : 0.f;
            accO[rb][cb][r] += v;
          }
          acc[rb][cb] = (ffrag)0.f;
        }
    }
  }
  const int ldc = T->ldc;
#pragma unroll
  for (int rb = 0; rb < 4; ++rb)
#pragma unroll
    for (int cb = 0; cb < 2; ++cb) {
      int col = colbase + cb * 16 + m16;
#pragma unroll
      for (int r = 0; r < 4; ++r) {
        int row = row0 + rb * 16 + kq * 4 + r;
        if (row < n) {
          float v = accO[rb][cb][r];
          if (T->R) v += b2f(T->R[(size_t)row * ldc + col]);
          T->C[(size_t)row * ldc + col] = f2b(v);
        }
      }
    }
}

// MFMA embed from raw flag-dtype A, 32-row tile, BK=64.
// REGISTER DOUBLE-BUFFERED staging (same scheme as mg_body); K need not be
// a multiple of 64 (guards preserved).
__device__ void embed_body(const ETask& T, int lx, int bf) {
  const int n = T.n;
  const int row0 = lx * 32;
  if (row0 >= n) return;
  __shared__ __align__(16) unsigned short As[32][72];
  __shared__ __align__(16) unsigned short Ws[128][72];
  const int t = threadIdx.x;
  const int wave = t >> 6, lane = t & 63;
  const int m16 = lane & 15, kq = lane >> 4;
  const int K = T.K;
  const int rbase = t >> 3, col8 = (t & 7) * 8;
  const int arow = row0 + rbase;
  ffrag acc[2][2];
#pragma unroll
  for (int i = 0; i < 2; ++i)
#pragma unroll
    for (int j = 0; j < 2; ++j) acc[i][j] = (ffrag)0.f;
  const int colbase = wave * 32;
  int4 aR; int4 wR[4];
  {  // prefetch k0 = 0
    int k = col8;
    int4 v = {0, 0, 0, 0};
    if (arow < n && k < K) v = ld8(T.A, (size_t)arow * K + k, bf);
    aR = v;
#pragma unroll
    for (int j = 0; j < 4; ++j) {
      int4 w = {0, 0, 0, 0};
      if (k < K) w = *(const int4*)(T.W + (size_t)(rbase + 32 * j) * K + k);
      wR[j] = w;
    }
  }
  for (int k0 = 0; k0 < K; k0 += 64) {
    *(int4*)&As[rbase][col8] = aR;
#pragma unroll
    for (int j = 0; j < 4; ++j) *(int4*)&Ws[rbase + 32 * j][col8] = wR[j];
    if (k0 + 64 < K) {  // issue next step's loads
      int k = k0 + 64 + col8;
      int4 v = {0, 0, 0, 0};
      if (arow < n && k < K) v = ld8(T.A, (size_t)arow * K + k, bf);
      aR = v;
#pragma unroll
      for (int j = 0; j < 4; ++j) {
        int4 w = {0, 0, 0, 0};
        if (k < K) w = *(const int4*)(T.W + (size_t)(rbase + 32 * j) * K + k);
        wR[j] = w;
      }
    }
    __syncthreads();
#pragma unroll
    for (int kk = 0; kk < 64; kk += 32) {
      bfrag a0 = *(const bfrag*)&As[m16][kk + kq * 8];
      bfrag a1 = *(const bfrag*)&As[16 + m16][kk + kq * 8];
      bfrag b0 = *(const bfrag*)&Ws[colbase + m16][kk + kq * 8];
      bfrag b1 = *(const bfrag*)&Ws[colbase + 16 + m16][kk + kq * 8];
      acc[0][0] = __builtin_amdgcn_mfma_f32_16x16x32_bf16(a0, b0, acc[0][0], 0, 0, 0);
      acc[0][1] = __builtin_amdgcn_mfma_f32_16x16x32_bf16(a0, b1, acc[0][1], 0, 0, 0);
      acc[1][0] = __builtin_amdgcn_mfma_f32_16x16x32_bf16(a1, b0, acc[1][0], 0, 0, 0);
      acc[1][1] = __builtin_amdgcn_mfma_f32_16x16x32_bf16(a1, b1, acc[1][1], 0, 0, 0);
    }
    __syncthreads();
  }
#pragma unroll
  for (int rb = 0; rb < 2; ++rb)
#pragma unroll
    for (int cb = 0; cb < 2; ++cb) {
      int col = colbase + cb * 16 + m16;
      float bv = T.bias[col];
#pragma unroll
      for (int r = 0; r < 4; ++r) {
        int row = row0 + rb * 16 + kq * 4 + r;
        if (row < n) {
          float v = acc[rb][cb][r] + bv;
          T.C[(size_t)row * T.ldc + col] = f2b(v > 0.f ? v : 0.f);
        }
      }
    }
}

// ---------------- kernels ----------------

__global__ void k_flag(const unsigned int* probe, int* flag) {
  if (threadIdx.x == 0) *flag = (probe[0] == 0x3F800000u) ? 0 : 1;
}

// CSR pass A: per-chunk LDS histogram; NO global atomics.
__launch_bounds__(256)
__global__ void k_csr_cnt(CsrArgs args, COff co) {
  __shared__ unsigned int h32[10000];  // 40000 B: covers n_dst <= 20000
  int bx = blockIdx.x, l = 0;
  while (l + 1 < NCSR && bx >= co.off[l + 1]) ++l;
  const int b = bx - co.off[l];
  const CsrDesc cd = args.d[l];
  const int nh = (cd.n_dst + 1) >> 1;
  for (int i = threadIdx.x; i < nh; i += 256) h32[i] = 0;
  __syncthreads();
  const int e0 = b << CLOG;
  const int e1 = min(e0 + CCHUNK, cd.E);
  for (int e = e0 + (int)threadIdx.x; e < e1; e += 256) {
    int d = cd.dst[e];
    unsigned int old = atomicAdd(&h32[d >> 1], (d & 1) ? 65536u : 1u);
    cd.slot16[e] = (unsigned short)((d & 1) ? (old >> 16) : (old & 0xFFFFu));
  }
  __syncthreads();
  unsigned int* cb = cd.cnt + (size_t)b * cd.n_dst;
  for (int i = threadIdx.x; i < cd.n_dst; i += 256)
    cb[i] = (i & 1) ? (h32[i >> 1] >> 16) : (h32[i >> 1] & 0xFFFFu);
}

// CSR pass B1: per-dst exclusive prefix over chunk histograms, PARALLEL over
// all (list,dst) pairs.
__launch_bounds__(256)
__global__ void k_csr_chunkpref(CsrArgs args, COff cp, int total) {
  int idx = blockIdx.x * 256 + (int)threadIdx.x;
  if (idx >= total) return;
  int l = 0;
  while (l + 1 < NCSR && idx >= cp.off[l + 1]) ++l;
  const int d = idx - cp.off[l];
  const CsrDesc cd = args.d[l];
  unsigned int s = 0;
  unsigned int* cc = cd.cnt + d;
  const int nb = cd.nb;
  for (int b = 0; b < nb; ++b) {
    unsigned int v = cc[(size_t)b * cd.n_dst];
    cc[(size_t)b * cd.n_dst] = s;
    s += v;
  }
  cd.rowptr[d + 1] = (int)s;
  if (d == 0) cd.rowptr[0] = 0;
}

// CSR pass B2: block-wide inclusive scan of rowptr (one block per list)
__global__ void k_csr_rowscan(CsrArgs args) {
  const CsrDesc cd = args.d[blockIdx.x];
  const int t = threadIdx.x;
  const int n = cd.n_dst + 1;
  const int lane = t & 63, w = t >> 6;
  __shared__ int wsum[16];
  int carry = 0;
  for (int base = 0; base < n; base += 1024) {
    int i = base + t;
    int v = (i < n) ? cd.rowptr[i] : 0;
    for (int off = 1; off < 64; off <<= 1) {
      int u = __shfl_up(v, off, 64);
      if (lane >= off) v += u;
    }
    if (lane == 63) wsum[w] = v;
    __syncthreads();
    if (w == 0) {
      int s = (lane < 16) ? wsum[lane] : 0;
      for (int off = 1; off < 16; off <<= 1) {
        int u = __shfl_up(s, off, 64);
        if (lane >= off) s += u;
      }
      if (lane < 16) wsum[lane] = s;
    }
    __syncthreads();
    int nv = v + carry + (w > 0 ? wsum[w - 1] : 0);
    if (i < n) cd.rowptr[i] = nv;
    carry += wsum[15];
    __syncthreads();
  }
}

// merged embed + biasrelu (no atomics, both MFMA/stream friendly)
__launch_bounds__(256)
__global__ void k_eb(EArgs ea, BArgs ba, const int* __restrict__ flagp) {
  int bx = blockIdx.x;
  if (bx < 1032) {  // embed prefix {0,250,875,1032} for n = 8000/20000/5000, 32-row tiles
    int t, lx;
    if (bx < 250) { t = 0; lx = bx; }
    else if (bx < 875) { t = 1; lx = bx - 250; }
    else { t = 2; lx = bx - 875; }
    embed_body(ea.t[t], lx, *flagp);
    return;
  }
  bx -= 1032;
  bias_body(ba.t[bx >> 7], bx & 127, *flagp);
}

// merged param+weight conversion: [params 21x4][weights 37x32]
__launch_bounds__(256)
__global__ void k_cv(PArgs pa, WArgs wa, const int* __restrict__ flagp) {
  const int bf = *flagp;
  int bx = blockIdx.x;
  if (bx < NPT * 4) {
    const PTask T = pa.t[bx >> 2];
    for (int i = (bx & 3) * 256 + (int)threadIdx.x; i < T.n; i += 4 * 256)
      T.dst[i] = ldf(T.src, (size_t)i, bf);
  } else {
    bx -= NPT * 4;
    const WTask T = wa.t[bx >> 5];
    const int lx = bx & 31;
    const int total = T.K * T.N;
    const size_t eoff = (size_t)T.eoff;
    for (int i = lx * 256 + (int)threadIdx.x; i < total; i += 32 * 256) {
      int n = i / T.K, k = i - n * T.K;
      T.dst[i] = f2b(ldf(T.src, eoff + (size_t)k * T.N + n, bf));
    }
  }
}

// super: [csr_fill 15x96][mg flat]
__launch_bounds__(256)
__global__ void k_fillmg(CsrArgs csr, MSup ms) {
  int bx = blockIdx.x;
  if (bx < NCSR * 96) { fill_body(csr.d[bx / 96], bx % 96); return; }
  bx -= NCSR * 96;
  int lx; int t = find_task(ms.off, ms.nt, bx, lx);
  mg_body(&ms.t[t], lx);
}

// pure gather super (no LDS -> full occupancy)
__global__ void k_gsup(GSup gs) {
  int lx; int t = find_task(gs.off, gs.nt, blockIdx.x, lx);
  gather_body(gs.t[t], lx);
}

// combined gather + mg super
__launch_bounds__(256)
__global__ void k_gm(GSup gs, MSup ms) {
  int bx = blockIdx.x;
  const int gtot = gs.off[gs.nt];
  if (bx < gtot) {
    int lx; int t = find_task(gs.off, gs.nt, bx, lx);
    gather_body(gs.t[t], lx);
    return;
  }
  bx -= gtot;
  int lx; int t = find_task(ms.off, ms.nt, bx, lx);
  mg_body(&ms.t[t], lx);
}

// MFMA GEMM with BN+relu applied to bf16 A while staging; 64-row tile; BK=64
// FUSED per-column sum/sumsq of the pre-bf16 output into st
template<int NC>
__launch_bounds__(256)
__global__ void k_gemm_bn(const unsigned short* __restrict__ A, const unsigned short* __restrict__ W,
                          const float* __restrict__ bias, const float* __restrict__ ss,
                          unsigned short* __restrict__ C, double* __restrict__ st, int n, int K) {
  constexpr int CB = NC / 64;
  __shared__ __align__(16) unsigned short As[64][72];
  __shared__ __align__(16) unsigned short Ws[NC][72];
  const int t = threadIdx.x;
  const int wave = t >> 6, lane = t & 63;
  const int m16 = lane & 15, kq = lane >> 4;
  const int row0 = blockIdx.x * 64;
  if (row0 >= n) return;
  ffrag acc[4][CB];
#pragma unroll
  for (int i = 0; i < 4; ++i)
#pragma unroll
    for (int j = 0; j < CB; ++j) acc[i][j] = (ffrag)0.f;
  const int colbase = wave * 16 * CB;
  for (int k0 = 0; k0 < K; k0 += 64) {
    __syncthreads();
#pragma unroll
    for (int e = t; e < 512; e += 256) {
      int r = e >> 3, c = e & 7;
      int row = row0 + r, k = k0 + c * 8;
      int4 v = {0, 0, 0, 0};
      if (row < n) {
        int4 a8 = *(const int4*)(A + (size_t)row * K + k);
        const unsigned short* pa = (const unsigned short*)&a8;
        unsigned short o[8];
#pragma unroll
        for (int j = 0; j < 8; ++j) {
          float val = fmaf(b2f(pa[j]), ss[k + j], ss[K + k + j]);
          o[j] = f2b(val > 0.f ? val : 0.f);
        }
        v = *(const int4*)o;
      }
      *(int4*)&As[r][c * 8] = v;
    }
#pragma unroll
    for (int e = t; e < NC * 8; e += 256) {
      int nn = e >> 3, c = e & 7;
      *(int4*)&Ws[nn][c * 8] = *(const int4*)(W + (size_t)nn * K + k0 + c * 8);
    }
    __syncthreads();
#pragma unroll
    for (int kk = 0; kk < 64; kk += 32) {
#pragma unroll
      for (int cb = 0; cb < CB; ++cb) {
        bfrag b = *(const bfrag*)&Ws[colbase + cb * 16 + m16][kk + kq * 8];
#pragma unroll
        for (int rb = 0; rb < 4; ++rb) {
          bfrag a = *(const bfrag*)&As[rb * 16 + m16][kk + kq * 8];
          acc[rb][cb] = __builtin_amdgcn_mfma_f32_16x16x32_bf16(a, b, acc[rb][cb], 0, 0, 0);
        }
      }
    }
  }
#pragma unroll
  for (int cb = 0; cb < CB; ++cb) {
    int col = colbase + cb * 16 + m16;
    float bv = bias[col];
    float cs = 0.f, cq = 0.f;
#pragma unroll
    for (int rb = 0; rb < 4; ++rb) {
#pragma unroll
      for (int r = 0; r < 4; ++r) {
        int row = row0 + rb * 16 + kq * 4 + r;
        if (row < n) {
          float v = acc[rb][cb][r] + bv;
          C[(size_t)row * NC + col] = f2b(v);
          cs += v; cq += v * v;
        }
      }
    }
    cs += __shfl_xor(cs, 16); cs += __shfl_xor(cs, 32);
    cq += __shfl_xor(cq, 16); cq += __shfl_xor(cq, 32);
    if (kq == 0) {
      atomicAdd(&st[col], (double)cs);
      atomicAdd(&st[NC + col], (double)cq);
    }
  }
}

// BN1 stats over implicit z1[b] = Udr[x_dr[b]] + Up[x_p[b]]
__global__ void k_hstat(const int* __restrict__ xdr, const int* __restrict__ xp,
                        const unsigned short* __restrict__ Udr, const unsigned short* __restrict__ Up,
                        double* __restrict__ st, int B) {
  __shared__ double sS[4][256];
  __shared__ double sQ[4][256];
  const int t = threadIdx.x;
  const int lane = t & 63, w = t >> 6;
  const int c4 = lane * 4;
  double s0 = 0, s1 = 0, s2 = 0, s3 = 0, q0 = 0, q1 = 0, q2 = 0, q3 = 0;
  const int NW = gridDim.x * 4;
  for (int r = blockIdx.x * 4 + w; r < B; r += NW) {
    int i = xdr[r], j = xp[r];
    uint2 a = *(const uint2*)(Udr + (size_t)i * 256 + c4);
    uint2 b = *(const uint2*)(Up + (size_t)j * 256 + c4);
    float v0 = b2f((unsigned short)a.x) + b2f((unsigned short)b.x);
    float v1 = b2f((unsigned short)(a.x >> 16)) + b2f((unsigned short)(b.x >> 16));
    float v2 = b2f((unsigned short)a.y) + b2f((unsigned short)b.y);
    float v3 = b2f((unsigned short)(a.y >> 16)) + b2f((unsigned short)(b.y >> 16));
    s0 += v0; s1 += v1; s2 += v2; s3 += v3;
    q0 += (double)v0 * (double)v0; q1 += (double)v1 * (double)v1;
    q2 += (double)v2 * (double)v2; q3 += (double)v3 * (double)v3;
  }
  sS[w][c4] = s0; sS[w][c4 + 1] = s1; sS[w][c4 + 2] = s2; sS[w][c4 + 3] = s3;
  sQ[w][c4] = q0; sQ[w][c4 + 1] = q1; sQ[w][c4 + 2] = q2; sQ[w][c4 + 3] = q3;
  __syncthreads();
  double ts = sS[0][t] + sS[1][t] + sS[2][t] + sS[3][t];
  double tq = sQ[0][t] + sQ[1][t] + sQ[2][t] + sQ[3][t];
  atomicAdd(&st[t], ts);
  atomicAdd(&st[256 + t], tq);
}

// MLP layer 2: A gathered on the fly, BN1+relu inline; BK=64; fused col stats
__launch_bounds__(256)
__global__ void k_gemm_bn1(const int* __restrict__ xdr, const int* __restrict__ xp,
                           const unsigned short* __restrict__ Udr, const unsigned short* __restrict__ Up,
                           const unsigned short* __restrict__ W, const float* __restrict__ bias,
                           const float* __restrict__ ss, unsigned short* __restrict__ Co,
                           double* __restrict__ st, int n) {
  __shared__ __align__(16) unsigned short As[64][72];
  __shared__ __align__(16) unsigned short Ws[128][72];
  __shared__ int gi[64], gj[64];
  const int t = threadIdx.x;
  const int wave = t >> 6, lane = t & 63;
  const int m16 = lane & 15, kq = lane >> 4;
  const int row0 = blockIdx.x * 64;
  if (row0 >= n) return;
  if (t < 64) {
    int row = row0 + t; if (row >= n) row = n - 1;
    gi[t] = xdr[row]; gj[t] = xp[row];
  }
  ffrag acc[4][2];
#pragma unroll
  for (int i = 0; i < 4; ++i)
#pragma unroll
    for (int j = 0; j < 2; ++j) acc[i][j] = (ffrag)0.f;
  const int colbase = wave * 32;
  __syncthreads();
  for (int k0 = 0; k0 < 256; k0 += 64) {
    __syncthreads();
#pragma unroll
    for (int e = t; e < 512; e += 256) {
      int r = e >> 3, seg = e & 7;
      int k = k0 + seg * 8;
      int4 a = *(const int4*)(Udr + (size_t)gi[r] * 256 + k);
      int4 b = *(const int4*)(Up + (size_t)gj[r] * 256 + k);
      const unsigned short* pa = (const unsigned short*)&a;
      const unsigned short* pb = (const unsigned short*)&b;
      unsigned short o[8];
#pragma unroll
      for (int jj = 0; jj < 8; ++jj) {
        float v = b2f(pa[jj]) + b2f(pb[jj]);
        v = fmaf(v, ss[k + jj], ss[256 + k + jj]);
        o[jj] = f2b(v > 0.f ? v : 0.f);
      }
      *(int4*)&As[r][seg * 8] = *(const int4*)o;
    }
#pragma unroll
    for (int e = t; e < 1024; e += 256) {
      int nn = e >> 3, c = e & 7;
      *(int4*)&Ws[nn][c * 8] = *(const int4*)(W + (size_t)nn * 256 + k0 + c * 8);
    }
    __syncthreads();
#pragma unroll
    for (int kk = 0; kk < 64; kk += 32) {
      bfrag b0 = *(const bfrag*)&Ws[colbase + m16][kk + kq * 8];
      bfrag b1 = *(const bfrag*)&Ws[colbase + 16 + m16][kk + kq * 8];
#pragma unroll
      for (int rb = 0; rb < 4; ++rb) {
        bfrag a = *(const bfrag*)&As[rb * 16 + m16][kk + kq * 8];
        acc[rb][0] = __builtin_amdgcn_mfma_f32_16x16x32_bf16(a, b0, acc[rb][0], 0, 0, 0);
        acc[rb][1] = __builtin_amdgcn_mfma_f32_16x16x32_bf16(a, b1, acc[rb][1], 0, 0, 0);
      }
    }
  }
#pragma unroll
  for (int cb = 0; cb < 2; ++cb) {
    int col = colbase + cb * 16 + m16;
    float bv = bias[col];
    float cs = 0.f, cq = 0.f;
#pragma unroll
    for (int rb = 0; rb < 4; ++rb) {
#pragma unroll
      for (int r = 0; r < 4; ++r) {
        int row = row0 + rb * 16 + kq * 4 + r;
        if (row < n) {
          float v = acc[rb][cb][r] + bv;
          Co[(size_t)row * 128 + col] = f2b(v);
          cs += v; cq += v * v;
        }
      }
    }
    cs += __shfl_xor(cs, 16); cs += __shfl_xor(cs, 32);
    cq += __shfl_xor(cq, 16); cq += __shfl_xor(cq, 32);
    if (kq == 0) {
      atomicAdd(&st[col], (double)cs);
      atomicAdd(&st[128 + col], (double)cq);
    }
  }
}

__global__ void k_bnfin(const double* __restrict__ st, int B, int C,
                        const float* __restrict__ g, const float* __restrict__ be,
                        float* __restrict__ ss) {
  int c = threadIdx.x;
  if (c < C) {
    double m = st[c] / B;
    double v = st[C + c] / B - m * m;
    if (v < 0) v = 0;
    float sc = (float)((double)g[c] / sqrt(v + 1e-5));
    ss[c] = sc;
    ss[C + c] = be[c] - (float)m * sc;
  }
}

__global__ void k_final(const unsigned short* __restrict__ Z3, const float* __restrict__ ss3,
                        const float* __restrict__ Wo, const float* __restrict__ bo,
                        void* __restrict__ out, int B, const int* __restrict__ flagp) {
  __shared__ float w[64], sc[64], sh[64];
  if (threadIdx.x < 64) {
    w[threadIdx.x] = Wo[threadIdx.x];
    sc[threadIdx.x] = ss3[threadIdx.x];
    sh[threadIdx.x] = ss3[64 + threadIdx.x];
  }
  __syncthreads();
  const int bf = *flagp;
  const float bb = bo[0];
  for (int r = blockIdx.x * blockDim.x + threadIdx.x; r < B; r += gridDim.x * blockDim.x) {
    const unsigned short* z = &Z3[(size_t)r * 64];
    float acc = bb;
#pragma unroll
    for (int k = 0; k < 64; ++k) {
      float y = fmaf(b2f(z[k]), sc[k], sh[k]);
      y = y > 0.f ? y : 0.f;
      acc = fmaf(y, w[k], acc);
    }
    float sv = 1.f / (1.f + expf(-acc));
    if (bf) ((unsigned short*)out)[r] = f2b(sv);
    else ((float*)out)[r] = sv;
  }
}

extern "C" void kernel_launch(void* const* d_in, const int* in_sizes, int n_in,
                              void* d_out, int out_size, void* d_ws, size_t ws_size,
                              hipStream_t stream) {
  enum { N_DR = 8000, N_P = 20000, N_DIS = 5000, N_MF = 3000, N_BP = 8000,
         N_CC = 2000, N_PATH = 2392 };
  if (n_in < 59) return;
  const int B = in_sizes[0];
  const int* x_dr = (const int*)d_in[0];
  const int* x_p  = (const int*)d_in[1];

  char* base = (char*)d_ws;
  size_t off = 0;
  auto alloc = [&](size_t bytes) -> void* {
    void* p = base + off;
    off += (bytes + 255) & ~(size_t)255;
    return p;
  };
  int*    flagp = (int*)alloc(256);
  double* st1 = (double*)alloc(896 * sizeof(double));
  double* st2 = st1 + 512; double* st3 = st2 + 256;
  float*  ss1 = (float*)alloc(896 * sizeof(float));
  float*  ss2 = ss1 + 512; float* ss3 = ss2 + 256;
  float*  pbuf = (float*)alloc(6000 * sizeof(float));
  unsigned short* wbf = (unsigned short*)alloc(1100000 * 2);
  unsigned short* DR  = (unsigned short*)alloc((size_t)N_DR * 384 * 2);
  unsigned short* P   = (unsigned short*)alloc((size_t)N_P * 512 * 2);
  unsigned short* h_d = (unsigned short*)alloc((size_t)N_DIS * 128 * 2);
  unsigned short* d1b = (unsigned short*)alloc((size_t)N_DIS * 128 * 2);
  unsigned short* z1  = (unsigned short*)alloc((size_t)B * 256 * 2);
  char* arena = (char*)alloc(46u * 1024 * 1024);
  if (off > ws_size) return;

  // ---- arena layout (ushort units) ----
  unsigned short* ar = (unsigned short*)arena;
  unsigned short* A_hmf  = ar;
  unsigned short* A_hbp  = A_hmf + (size_t)N_MF * 128;
  unsigned short* A_hcc  = A_hbp + (size_t)N_BP * 128;
  unsigned short* A_hpath= A_hcc + (size_t)N_CC * 128;
  unsigned short* A_gomf = A_hpath + (size_t)N_PATH * 128;
  unsigned short* A_gobp = A_gomf + (size_t)N_MF * 128;
  unsigned short* A_gocc = A_gobp + (size_t)N_BP * 128;
  unsigned short* ag17 = A_gocc + (size_t)N_CC * 128;
  unsigned short* ag18 = ag17 + (size_t)N_MF * 128;
  unsigned short* ag9  = ag18 + (size_t)N_BP * 128;
  unsigned short* ag10 = ag9  + (size_t)N_DR * 128;
  unsigned short* ag11 = ag10 + (size_t)N_DR * 128;
  unsigned short* ag12 = ag11 + (size_t)N_P * 128;
  unsigned short* ag13 = ag12 + (size_t)N_DIS * 128;
  unsigned short* ag14 = ag13 + (size_t)N_DIS * 128;
  unsigned short* ag15 = ag14 + (size_t)N_DIS * 128;
  unsigned short* ag16 = ag15 + (size_t)N_DR * 128;
  unsigned short* ag21 = ag16 + (size_t)N_P * 128;
  unsigned short* ag22 = ag21 + (size_t)N_P * 128;
  unsigned short* ag23 = ag22 + (size_t)N_P * 128;
  unsigned short* U_dr = ar;
  unsigned short* U_p  = U_dr + (size_t)N_DR * 256;
  unsigned short* z2 = U_p + (size_t)N_P * 256;
  unsigned short* z3 = z1;
  // CSR scratch (slot16 + cnt) at arena elems 7.168M+ (z2 region): written by
  // cnt/chunkpref, read by fill; dead before ag11+ writes at L5 and z2 at bn1.
  unsigned short* slot_base = ar + (size_t)7168000;

  // L0: CSR pass A (depends only on edge inputs)
  const int list_ei[NCSR] = {9, 10, 11, 12, 13, 14, 15, 16, 17, 18, 19, 20, 21, 22, 23};
  const int list_nd[NCSR] = {N_DR, N_DR, N_P, N_DIS, N_DIS, N_DIS, N_DR, N_P,
                             N_MF, N_BP, N_CC, N_P, N_P, N_P, N_P};
  int* rp[24]; unsigned short* cs[24];
  CsrArgs csra;
  COff coff, cpref;
  unsigned short* csr_end;
  {
    // rowptr + csrc live in z1 head
    int* ip = (int*)z1;
    for (int l = 0; l < NCSR; ++l) { csra.d[l].rowptr = ip; rp[list_ei[l]] = ip; ip += list_nd[l] + 1; }
    unsigned short* up = (unsigned short*)ip;
    unsigned short* sp = slot_base;
    for (int l = 0; l < NCSR; ++l) {
      int ei = list_ei[l];
      int E = in_sizes[ei] / 2;
      csra.d[l].src = (const int*)d_in[ei];
      csra.d[l].dst = (const int*)d_in[ei] + E;
      csra.d[l].E = E;
      csra.d[l].n_dst = list_nd[l];
      csra.d[l].nb = (E + CCHUNK - 1) >> CLOG;
      csra.d[l].csrc = up; cs[ei] = up;
      csra.d[l].slot16 = sp;
      up += E;
      sp += E;
    }
    csr_end = up;
    unsigned int* cp = (unsigned int*)(((uintptr_t)sp + 255) & ~(uintptr_t)255);
    coff.off[0] = 0;
    cpref.off[0] = 0;
    for (int l = 0; l < NCSR; ++l) {
      csra.d[l].cnt = cp;
      cp += (size_t)csra.d[l].nb * csra.d[l].n_dst;
      coff.off[l + 1] = coff.off[l] + csra.d[l].nb;
      cpref.off[l + 1] = cpref.off[l] + csra.d[l].n_dst;
    }
  }
  k_csr_cnt<<<coff.off[NCSR], 256, 0, stream>>>(csra, coff);

  k_flag<<<1, 64, 0, stream>>>((const unsigned int*)d_in[5], flagp);

  // ---- L1: merged conversions ----
  float* pp[59] = {};
  PArgs pa;
  {
    const int pidx[NPT] = {25,27,29,31,33,35,37,39,41,44,46,47,48,50,51,52,54,55,56,57,58};
    size_t poff = 0;
    for (int l = 0; l < NPT; ++l) {
      int i = pidx[l];
      pa.t[l].src = d_in[i]; pa.t[l].dst = pbuf + poff; pa.t[l].n = in_sizes[i]; pa.t[l].pad = 0;
      pp[i] = pbuf + poff;
      poff += in_sizes[i];
    }
  }
  unsigned short *Wdr_t, *Wpe_t, *Wde_t, *Wg_t, *Wps_t, *Wss_t, *Wns_t, *W1_t, *W2_t, *W3_t;
  WArgs wa;
  {
    int l = 0; size_t woff = 0;
    auto add = [&](int inIdx, int eoff, int K, int N) -> unsigned short* {
      unsigned short* dst = wbf + woff;
      wa.t[l].src = d_in[inIdx]; wa.t[l].dst = dst; wa.t[l].K = K; wa.t[l].N = N;
      wa.t[l].eoff = eoff; wa.t[l].pad = 0;
      ++l; woff += (size_t)K * N;
      return dst;
    };
    Wdr_t = add(24, 0, 1024, 128);
    Wpe_t = add(26, 0, 400, 128);
    Wde_t = add(28, 0, 512, 128);
    Wg_t = wbf + woff;
    for (int j = 0; j < 7; ++j) add(38, j * 16384, 128, 128);
    Wps_t = wbf + woff;
    for (int j = 0; j < 8; ++j) add(40, j * 16384, 128, 128);
    Wss_t = wbf + woff;
    for (int j = 0; j < 8; ++j) add(42, j * 16384, 128, 128);
    Wns_t = wbf + woff;
    for (int j = 0; j < 8; ++j) add(43, j * 16384, 128, 128);
    W1_t = add(45, 0, 896, 256);
    W2_t = add(49, 0, 256, 128);
    W3_t = add(53, 0, 128, 64);
  }
  k_cv<<<NPT * 4 + NWT * 32, 256, 0, stream>>>(pa, wa, flagp);

  // pl0-7, ag19, ag20 in z1 after CSR content
  unsigned short* plb = (unsigned short*)(((uintptr_t)csr_end + 255) & ~(uintptr_t)255);
  unsigned short* plz0 = plb;
  unsigned short* plz1 = plz0 + (size_t)N_DIS * 128;
  unsigned short* plz2 = plz1 + (size_t)N_DIS * 128;
  unsigned short* plz3 = plz2 + (size_t)N_DIS * 128;
  unsigned short* plz4 = plz3 + (size_t)N_DR * 128;
  unsigned short* plz5 = plz4 + (size_t)N_DR * 128;
  unsigned short* plz6 = plz5 + (size_t)N_P * 128;
  unsigned short* plz7 = plz6 + (size_t)N_DR * 128;
  unsigned short* ag19 = plz7 + (size_t)N_P * 128;
  unsigned short* ag20 = ag19 + (size_t)N_CC * 128;
  if ((ag20 + (size_t)N_P * 128) > (z1 + (size_t)B * 256)) return;  // capacity guard

  hipMemsetAsync(st1, 0, 896 * sizeof(double), stream);

  auto mkpass = [](MTask& T, int i, const unsigned short* A, int lda, const unsigned short* W,
                   int ldw, const float* bias, int end) {
    T.p[i].A = A; T.p[i].lda = lda; T.p[i].W = W; T.p[i].ldw = ldw;
    T.p[i].bias = bias; T.p[i].flags = end;
  };
  const float* bg = pp[39];
  const float* bp_s = pp[41];
  const float* b_s = pp[44];

  auto gadd = [](GSup& g, GTask t) {
    if (g.nt == 0) g.off[0] = 0;
    g.t[g.nt] = t;
    g.off[g.nt + 1] = g.off[g.nt] + (t.n_dst + 3) / 4;
    g.nt++;
  };
  auto madd = [](MSup& m, const MTask& t) {
    if (m.nt == 0) m.off[0] = 0;
    m.t[m.nt] = t;
    m.off[m.nt + 1] = m.off[m.nt] + (t.n + 63) / 64;
    m.nt++;
  };

  // ---- L2: embed + biasrelu (atomic-free) ----
  {
    EArgs ea;
    ea.t[0] = {d_in[2], Wdr_t, pp[25], DR, N_DR, 1024, 384, 0};
    ea.t[1] = {d_in[3], Wpe_t, pp[27], P, N_P, 400, 512, 0};
    ea.t[2] = {d_in[4], Wde_t, pp[29], h_d, N_DIS, 512, 128, 0};
    BArgs ba;
    ba.t[0] = {d_in[30], pp[31], A_hmf, N_MF * 128, {}};
    ba.t[1] = {d_in[32], pp[33], A_hbp, N_BP * 128, {}};
    ba.t[2] = {d_in[34], pp[35], A_hcc, N_CC * 128, {}};
    ba.t[3] = {d_in[36], pp[37], A_hpath, N_PATH * 128, {}};
    k_eb<<<1032 + 4 * 128, 256, 0, stream>>>(ea, ba, flagp);
  }

  // ---- L3: CSR pass B (parallel chunk-prefix, then per-list row scan) ----
  k_csr_chunkpref<<<(cpref.off[NCSR] + 255) / 256, 256, 0, stream>>>(csra, cpref, cpref.off[NCSR]);
  k_csr_rowscan<<<NCSR, 1024, 0, stream>>>(csra);

  // ---- L4: csr_fill || SAGE-pool-8 GEMM (pl* -> z1) ----
  {
    MSup ms; ms.nt = 0;
    const unsigned short* xs[8] = {h_d, h_d, h_d, DR, DR, P, DR, P};
    const int lda[8] = {128, 128, 128, 384, 384, 512, 384, 512};
    const int nn[8] = {N_DIS, N_DIS, N_DIS, N_DR, N_DR, N_P, N_DR, N_P};
    unsigned short* plo[8] = {plz0, plz1, plz2, plz3, plz4, plz5, plz6, plz7};
    for (int i = 0; i < 8; ++i) {
      MTask T;
      mkpass(T, 0, xs[i], lda[i], Wps_t + (size_t)i * 16384, 128, bp_s + i * 128, 1);
      T.npass = 1; T.n = nn[i]; T.K = 128; T.R = nullptr; T.C = plo[i]; T.ldc = 128; T.relu = 1;
      madd(ms, T);
    }
    k_fillmg<<<NCSR * 96 + ms.off[ms.nt], 256, 0, stream>>>(csra, ms);
  }

  // ---- L5: all first-round gathers (GO sims + SAGE pool) ----
  {
    GSup gs; gs.nt = 0;
    gadd(gs, {rp[17], cs[17], A_hmf, ag17, N_MF, 128, 0, 0});
    gadd(gs, {rp[18], cs[18], A_hbp, ag18, N_BP, 128, 0, 0});
    gadd(gs, {rp[19], cs[19], A_hcc, ag19, N_CC, 128, 0, 0});
    gadd(gs, {rp[9],  cs[9],  plz0, ag9,  N_DR, 128, 1, 0});
    gadd(gs, {rp[10], cs[10], plz1, ag10, N_DR, 128, 1, 0});
    gadd(gs, {rp[11], cs[11], plz2, ag11, N_P, 128, 1, 0});
    gadd(gs, {rp[12], cs[12], plz3, ag12, N_DIS, 128, 1, 0});
    gadd(gs, {rp[13], cs[13], plz4, ag13, N_DIS, 128, 1, 0});
    gadd(gs, {rp[14], cs[14], plz5, ag14, N_DIS, 128, 1, 0});
    gadd(gs, {rp[15], cs[15], plz6, ag15, N_DR, 128, 1, 0});
    gadd(gs, {rp[16], cs[16], plz7, ag16, N_P, 128, 1, 0});
    k_gsup<<<gs.off[gs.nt], 256, 0, stream>>>(gs);
  }

  GSup g0; g0.nt = 0; g0.off[0] = 0;  // empty gather section for pure-mg launches

  // ---- L6: GO-GCN (3) || hetero-combine-1 (3) ----
  {
    MSup ms; ms.nt = 0;
    for (int i = 0; i < 3; ++i) {
      MTask T;
      const unsigned short* aggp = (i == 0) ? ag17 : (i == 1) ? ag18 : ag19;
      const unsigned short* Rp = (i == 0) ? A_hmf : (i == 1) ? A_hbp : A_hcc;
      unsigned short* Cp = (i == 0) ? A_gomf : (i == 1) ? A_gobp : A_gocc;
      int n = (i == 0) ? N_MF : (i == 1) ? N_BP : N_CC;
      mkpass(T, 0, aggp, 128, Wg_t + (size_t)i * 16384, 128, bg + i * 128, 1);
      T.npass = 1; T.n = n; T.K = 128; T.R = Rp; T.C = Cp; T.ldc = 128; T.relu = 1;
      madd(ms, T);
    }
    {
      MTask T;
      mkpass(T, 0, DR, 384, Wss_t + (size_t)0 * 16384, 128, nullptr, 0);
      mkpass(T, 1, ag9, 128, Wns_t + (size_t)0 * 16384, 128, b_s + 0 * 128, 1);
      mkpass(T, 2, DR, 384, Wss_t + (size_t)1 * 16384, 128, nullptr, 0);
      mkpass(T, 3, ag10, 128, Wns_t + (size_t)1 * 16384, 128, b_s + 1 * 128, 1);
      mkpass(T, 4, DR, 384, Wss_t + (size_t)6 * 16384, 128, nullptr, 0);
      mkpass(T, 5, ag15, 128, Wns_t + (size_t)6 * 16384, 128, b_s + 6 * 128, 1);
      T.npass = 6; T.n = N_DR; T.K = 128; T.R = nullptr; T.C = DR + 128; T.ldc = 384; T.relu = 1;
      madd(ms, T);
    }
    {
      MTask T;
      mkpass(T, 0, P, 512, Wss_t + (size_t)2 * 16384, 128, nullptr, 0);
      mkpass(T, 1, ag11, 128, Wns_t + (size_t)2 * 16384, 128, b_s + 2 * 128, 1);
      mkpass(T, 2, P, 512, Wss_t + (size_t)7 * 16384, 128, nullptr, 0);
      mkpass(T, 3, ag16, 128, Wns_t + (size_t)7 * 16384, 128, b_s + 7 * 128, 1);
      T.npass = 4; T.n = N_P; T.K = 128; T.R = nullptr; T.C = P + 128; T.ldc = 512; T.relu = 1;
      madd(ms, T);
    }
    {
      MTask T;
      mkpass(T, 0, h_d, 128, Wss_t + (size_t)3 * 16384, 128, nullptr, 0);
      mkpass(T, 1, ag12, 128, Wns_t + (size_t)3 * 16384, 128, b_s + 3 * 128, 1);
      mkpass(T, 2, h_d, 128, Wss_t + (size_t)4 * 16384, 128, nullptr, 0);
      mkpass(T, 3, ag13, 128, Wns_t + (size_t)4 * 16384, 128, b_s + 4 * 128, 1);
      mkpass(T, 4, h_d, 128, Wss_t + (size_t)5 * 16384, 128, nullptr, 0);
      mkpass(T, 5, ag14, 128, Wns_t + (size_t)5 * 16384, 128, b_s + 5 * 128, 1);
      T.npass = 6; T.n = N_DIS; T.K = 128; T.R = nullptr; T.C = d1b; T.ldc = 128; T.relu = 1;
      madd(ms, T);
    }
    k_gm<<<ms.off[ms.nt], 256, 0, stream>>>(g0, ms);
  }

  // ---- L7: GO->P gathers (4) || SAGE-pool-2 (5) ----
  {
    GSup gs; gs.nt = 0;
    gadd(gs, {rp[20], cs[20], A_gomf, ag20, N_P, 128, 0, 0});
    gadd(gs, {rp[21], cs[21], A_gobp, ag21, N_P, 128, 0, 0});
    gadd(gs, {rp[22], cs[22], A_gocc, ag22, N_P, 128, 0, 0});
    gadd(gs, {rp[23], cs[23], A_hpath, ag23, N_P, 128, 0, 0});
    MSup ms; ms.nt = 0;
    const unsigned short* xs[5] = {d1b, d1b, d1b, DR + 128, P + 128};
    const int lda[5] = {128, 128, 128, 384, 512};
    const int nn[5] = {N_DIS, N_DIS, N_DIS, N_DR, N_P};
    unsigned short* plo[5] = {plz0, plz1, plz2, plz6, plz7};
    const int si[5] = {0, 1, 2, 6, 7};
    for (int i = 0; i < 5; ++i) {
      MTask T;
      mkpass(T, 0, xs[i], lda[i], Wps_t + (size_t)si[i] * 16384, 128, bp_s + si[i] * 128, 1);
      T.npass = 1; T.n = nn[i]; T.K = 128; T.R = nullptr; T.C = plo[i]; T.ldc = 128; T.relu = 1;
      madd(ms, T);
    }
    k_gm<<<gs.off[gs.nt] + ms.off[ms.nt], 256, 0, stream>>>(gs, ms);
  }

  // ---- L8: GO->P GEMM (1) || second-round gathers (5) ----
  {
    GSup gs; gs.nt = 0;
    gadd(gs, {rp[9],  cs[9],  plz0, ag9,  N_DR, 128, 1, 0});
    gadd(gs, {rp[10], cs[10], plz1, ag10, N_DR, 128, 1, 0});
    gadd(gs, {rp[11], cs[11], plz2, ag11, N_P, 128, 1, 0});
    gadd(gs, {rp[15], cs[15], plz6, ag15, N_DR, 128, 1, 0});
    gadd(gs, {rp[16], cs[16], plz7, ag16, N_P, 128, 1, 0});
    MSup ms; ms.nt = 0;
    MTask T;
    mkpass(T, 0, ag20, 128, Wg_t + 3 * 16384, 128, bg + 3 * 128, 1);
    mkpass(T, 1, ag21, 128, Wg_t + 4 * 16384, 128, bg + 4 * 128, 1);
    mkpass(T, 2, ag22, 128, Wg_t + 5 * 16384, 128, bg + 5 * 128, 1);
    mkpass(T, 3, ag23, 128, Wg_t + 6 * 16384, 128, bg + 6 * 128, 1);
    T.npass = 4; T.n = N_P; T.K = 128; T.R = nullptr; T.C = P + 384; T.ldc = 512; T.relu = 1;
    madd(ms, T);
    k_gm<<<gs.off[gs.nt] + ms.off[ms.nt], 256, 0, stream>>>(gs, ms);
  }

  // ---- L9: hetero-combine-2 (2) ----
  {
    MSup ms; ms.nt = 0;
    {
      MTask T;
      mkpass(T, 0, DR + 128, 384, Wss_t + (size_t)0 * 16384, 128, nullptr, 0);
      mkpass(T, 1, ag9, 128, Wns_t + (size_t)0 * 16384, 128, b_s + 0 * 128, 1);
      mkpass(T, 2, DR + 128, 384, Wss_t + (size_t)1 * 16384, 128, nullptr, 0);
      mkpass(T, 3, ag10, 128, Wns_t + (size_t)1 * 16384, 128, b_s + 1 * 128, 1);
      mkpass(T, 4, DR + 128, 384, Wss_t + (size_t)6 * 16384, 128, nullptr, 0);
      mkpass(T, 5, ag15, 128, Wns_t + (size_t)6 * 16384, 128, b_s + 6 * 128, 1);
      T.npass = 6; T.n = N_DR; T.K = 128; T.R = nullptr; T.C = DR + 256; T.ldc = 384; T.relu = 1;
      madd(ms, T);
    }
    {
      MTask T;
      mkpass(T, 0, P + 128, 512, Wss_t + (size_t)2 * 16384, 128, nullptr, 0);
      mkpass(T, 1, ag11, 128, Wns_t + (size_t)2 * 16384, 128, b_s + 2 * 128, 1);
      mkpass(T, 2, P + 128, 512, Wss_t + (size_t)7 * 16384, 128, nullptr, 0);
      mkpass(T, 3, ag16, 128, Wns_t + (size_t)7 * 16384, 128, b_s + 7 * 128, 1);
      T.npass = 4; T.n = N_P; T.K = 128; T.R = nullptr; T.C = P + 256; T.ldc = 512; T.relu = 1;
      madd(ms, T);
    }
    k_gm<<<ms.off[ms.nt], 256, 0, stream>>>(g0, ms);
  }

  // ---- L10: W1 GEMM (4) ----
  {
    MSup ms; ms.nt = 0;
    for (int half = 0; half < 2; ++half) {
      {
        MTask T;
        mkpass(T, 0, DR, 384, W1_t + (size_t)(half * 128) * 896, 896, pp[46] + half * 128, 1);
        T.npass = 1; T.n = N_DR; T.K = 384; T.R = nullptr;
        T.C = U_dr + half * 128; T.ldc = 256; T.relu = 0;
        madd(ms, T);
      }
      {
        MTask T;
        mkpass(T, 0, P, 512, W1_t + (size_t)(half * 128) * 896 + 384, 896, nullptr, 1);
        T.npass = 1; T.n = N_P; T.K = 512; T.R = nullptr;
        T.C = U_p + half * 128; T.ldc = 256; T.relu = 0;
        madd(ms, T);
      }
    }
    k_gm<<<ms.off[ms.nt], 256, 0, stream>>>(g0, ms);
  }

  // ---- MLP tail ----
  k_hstat<<<256, 256, 0, stream>>>(x_dr, x_p, U_dr, U_p, st1, B);
  k_bnfin<<<1, 256, 0, stream>>>(st1, B, 256, pp[47], pp[48], ss1);

  k_gemm_bn1<<<(B + 63) / 64, 256, 0, stream>>>(x_dr, x_p, U_dr, U_p, W2_t, pp[50], ss1, z2, st2, B);
  k_bnfin<<<1, 128, 0, stream>>>(st2, B, 128, pp[51], pp[52], ss2);

  k_gemm_bn<64><<<(B + 63) / 64, 256, 0, stream>>>(z2, W3_t, pp[54], ss2, z3, st3, B, 128);
  k_bnfin<<<1, 64, 0, stream>>>(st3, B, 64, pp[55], pp[56], ss3);

  k_final<<<256, 256, 0, stream>>>(z3, ss3, pp[57], pp[58], d_out, B, flagp);
}

// Round 13
// 1200.293 us; speedup vs baseline: 1.0403x; 1.0403x over previous
//
#include <hip/hip_runtime.h>

#define NCSR 15
#define MAXP 6
#define MAXT 8
#define MAXG 12
#define NPT 21
#define NWT 37
#define CLOG 14
#define CCHUNK 16384

typedef __attribute__((ext_vector_type(8))) short bfrag;
typedef __attribute__((ext_vector_type(4))) float ffrag;

__device__ __forceinline__ float b2f(unsigned short s) {
  return __uint_as_float(((unsigned int)s) << 16);
}
__device__ __forceinline__ unsigned short f2b(float f) {
  unsigned int u = __float_as_uint(f);
  u = (u + 0x7FFFu + ((u >> 16) & 1u)) >> 16;
  return (unsigned short)u;
}
__device__ __forceinline__ float ldf(const void* p, size_t i, int bf) {
  if (bf) return b2f(((const unsigned short*)p)[i]);
  return ((const float*)p)[i];
}
// load 8 consecutive raw elements (flag dtype) -> packed 8x bf16 in int4
__device__ __forceinline__ int4 ld8(const void* p, size_t i, int bf) {
  if (bf) return *(const int4*)((const unsigned short*)p + i);
  const float* pf = (const float*)p + i;
  float4 f0 = *(const float4*)pf;
  float4 f1 = *(const float4*)(pf + 4);
  int4 v;
  v.x = (int)((unsigned)f2b(f0.x) | ((unsigned)f2b(f0.y) << 16));
  v.y = (int)((unsigned)f2b(f0.z) | ((unsigned)f2b(f0.w) << 16));
  v.z = (int)((unsigned)f2b(f1.x) | ((unsigned)f2b(f1.y) << 16));
  v.w = (int)((unsigned)f2b(f1.z) | ((unsigned)f2b(f1.w) << 16));
  return v;
}

// CSR build WITHOUT global atomics: per-chunk LDS histogram (pass A) ->
// per-(chunk,dst) exclusive bases (pass B, parallel over all dsts) -> fill (pass C)
struct CsrDesc {
  const int* src; const int* dst; int* rowptr; unsigned short* csrc;
  unsigned short* slot16;   // per-edge rank within its chunk (u16, < CCHUNK)
  unsigned int* cnt;        // [nb][n_dst]: counts (pass A) -> exclusive bases (pass B)
  int E, n_dst, nb, pad;
};
struct CsrArgs { CsrDesc d[NCSR]; };
struct COff { int off[16]; };

struct PTask { const void* src; float* dst; int n; int pad; };
struct PArgs { PTask t[NPT]; };

struct WTask { const void* src; unsigned short* dst; int K; int N; int eoff; int pad; };
struct WArgs { WTask t[NWT]; };

struct MPass { const unsigned short* A; const unsigned short* W; const float* bias; int lda; int ldw; int flags; };
struct MTask {
  MPass p[MAXP];
  const unsigned short* R; unsigned short* C;
  int npass, n, K, ldc, relu, pad;
};

struct GTask { const int* rowptr; const unsigned short* csrc; const unsigned short* X; unsigned short* out; int n_dst; int ldx; int mode; int pad; };

struct ETask { const void* A; const unsigned short* W; const float* bias; unsigned short* C; int n, K, ldc, pad; };
struct EArgs { ETask t[3]; };

struct BTask { const void* w; const float* b; unsigned short* out; int n; int pad[3]; };
struct BArgs { BTask t[4]; };

// flat-packed super-launch descriptors: off[i] = first block-x of task i
struct GSup { GTask t[MAXG]; int off[MAXG + 1]; int nt; };
struct MSup { MTask t[MAXT]; int off[MAXT + 1]; int nt; };

__device__ __forceinline__ int find_task(const int* off, int nt, int bx, int& lx) {
  int t = 0;
  while (t + 1 < nt && bx >= off[t + 1]) ++t;
  lx = bx - off[t];
  return t;
}

// ---------------- device bodies ----------------

// pass C: deterministic fill, no atomics
__device__ void fill_body(const CsrDesc& cd, int lx) {
  for (int e = lx * 256 + (int)threadIdx.x; e < cd.E; e += 96 * 256) {
    int d = cd.dst[e];
    int pos = cd.rowptr[d] + (int)cd.cnt[(size_t)(e >> CLOG) * cd.n_dst + d]
              + (int)cd.slot16[e];
    cd.csrc[pos] = (unsigned short)cd.src[e];
  }
}

__device__ void bias_body(const BTask& T, int lx, int bf) {
  const int n8 = T.n >> 3;
  for (int i = lx * 256 + (int)threadIdx.x; i < n8; i += 128 * 256) {
    int base = i << 3;
    int4 v = ld8(T.w, (size_t)base, bf);
    const unsigned short* pv = (const unsigned short*)&v;
    const int cb = base & 127;
    unsigned short o[8];
#pragma unroll
    for (int j = 0; j < 8; ++j) {
      float f = b2f(pv[j]) + T.b[cb + j];
      o[j] = f2b(f > 0.f ? f : 0.f);
    }
    *(int4*)(T.out + base) = *(const int4*)o;
  }
}

// one wave per dst row; lane = one uint = 2 bf16 cols; 4-edge unroll
__device__ void gather_body(const GTask& T, int lx) {
  int w = lx * 4 + ((int)threadIdx.x >> 6);
  if (w >= T.n_dst) return;
  int lane = threadIdx.x & 63;
  int beg = T.rowptr[w], end = T.rowptr[w + 1];
  float a0 = 0.f, a1 = 0.f;
  int j = beg;
  if (T.mode == 0) {
    for (; j + 3 < end; j += 4) {
      unsigned int u0 = ((const unsigned int*)(T.X + (size_t)T.csrc[j] * T.ldx))[lane];
      unsigned int u1 = ((const unsigned int*)(T.X + (size_t)T.csrc[j + 1] * T.ldx))[lane];
      unsigned int u2 = ((const unsigned int*)(T.X + (size_t)T.csrc[j + 2] * T.ldx))[lane];
      unsigned int u3 = ((const unsigned int*)(T.X + (size_t)T.csrc[j + 3] * T.ldx))[lane];
      a0 += __uint_as_float(u0 << 16) + __uint_as_float(u1 << 16)
          + __uint_as_float(u2 << 16) + __uint_as_float(u3 << 16);
      a1 += __uint_as_float(u0 & 0xFFFF0000u) + __uint_as_float(u1 & 0xFFFF0000u)
          + __uint_as_float(u2 & 0xFFFF0000u) + __uint_as_float(u3 & 0xFFFF0000u);
    }
    for (; j < end; ++j) {
      unsigned int u0 = ((const unsigned int*)(T.X + (size_t)T.csrc[j] * T.ldx))[lane];
      a0 += __uint_as_float(u0 << 16);
      a1 += __uint_as_float(u0 & 0xFFFF0000u);
    }
  } else {
    for (; j + 3 < end; j += 4) {
      unsigned int u0 = ((const unsigned int*)(T.X + (size_t)T.csrc[j] * T.ldx))[lane];
      unsigned int u1 = ((const unsigned int*)(T.X + (size_t)T.csrc[j + 1] * T.ldx))[lane];
      unsigned int u2 = ((const unsigned int*)(T.X + (size_t)T.csrc[j + 2] * T.ldx))[lane];
      unsigned int u3 = ((const unsigned int*)(T.X + (size_t)T.csrc[j + 3] * T.ldx))[lane];
      a0 = fmaxf(fmaxf(a0, fmaxf(__uint_as_float(u0 << 16), __uint_as_float(u1 << 16))),
                 fmaxf(__uint_as_float(u2 << 16), __uint_as_float(u3 << 16)));
      a1 = fmaxf(fmaxf(a1, fmaxf(__uint_as_float(u0 & 0xFFFF0000u), __uint_as_float(u1 & 0xFFFF0000u))),
                 fmaxf(__uint_as_float(u2 & 0xFFFF0000u), __uint_as_float(u3 & 0xFFFF0000u)));
    }
    for (; j < end; ++j) {
      unsigned int u0 = ((const unsigned int*)(T.X + (size_t)T.csrc[j] * T.ldx))[lane];
      a0 = fmaxf(a0, __uint_as_float(u0 << 16));
      a1 = fmaxf(a1, __uint_as_float(u0 & 0xFFFF0000u));
    }
  }
  unsigned int* po = (unsigned int*)(T.out + (size_t)w * 128);
  po[lane] = (unsigned int)f2b(a0) | ((unsigned int)f2b(a1) << 16);
}

// MFMA multi-pass GEMM body, 64-row x 128-col tile, BK=64.
// REVERTED to simple staging (round-8 measured version): the reg-dbuf variant
// regressed mg-family kernels (~+50us) due to register pressure.
__device__ void mg_body(const MTask* T, int lx) {
  const int n = T->n;
  const int row0 = lx * 64;
  if (row0 >= n) return;
  __shared__ __align__(16) unsigned short As[64][72];
  __shared__ __align__(16) unsigned short Ws[128][72];
  const int t = threadIdx.x;
  const int wave = t >> 6, lane = t & 63;
  const int m16 = lane & 15, kq = lane >> 4;
  const int K = T->K;
  ffrag acc[4][2], accO[4][2];
#pragma unroll
  for (int i = 0; i < 4; ++i)
#pragma unroll
    for (int j = 0; j < 2; ++j) { acc[i][j] = (ffrag)0.f; accO[i][j] = (ffrag)0.f; }
  const int colbase = wave * 32;
  for (int ip = 0; ip < T->npass; ++ip) {
    const unsigned short* Ap = T->p[ip].A;
    const unsigned short* Wp = T->p[ip].W;
    const int lda = T->p[ip].lda, ldw = T->p[ip].ldw;
    for (int k0 = 0; k0 < K; k0 += 64) {
      __syncthreads();
#pragma unroll
      for (int e = t; e < 512; e += 256) {
        int r = e >> 3, c = e & 7;
        int row = row0 + r;
        int4 v = {0, 0, 0, 0};
        if (row < n) v = *(const int4*)(Ap + (size_t)row * lda + k0 + c * 8);
        *(int4*)&As[r][c * 8] = v;
      }
#pragma unroll
      for (int e = t; e < 1024; e += 256) {
        int nn = e >> 3, c = e & 7;
        *(int4*)&Ws[nn][c * 8] = *(const int4*)(Wp + (size_t)nn * ldw + k0 + c * 8);
      }
      __syncthreads();
#pragma unroll
      for (int kk = 0; kk < 64; kk += 32) {
        bfrag b0 = *(const bfrag*)&Ws[colbase + m16][kk + kq * 8];
        bfrag b1 = *(const bfrag*)&Ws[colbase + 16 + m16][kk + kq * 8];
#pragma unroll
        for (int rb = 0; rb < 4; ++rb) {
          bfrag a = *(const bfrag*)&As[rb * 16 + m16][kk + kq * 8];
          acc[rb][0] = __builtin_amdgcn_mfma_f32_16x16x32_bf16(a, b0, acc[rb][0], 0, 0, 0);
          acc[rb][1] = __builtin_amdgcn_mfma_f32_16x16x32_bf16(a, b1, acc[rb][1], 0, 0, 0);
        }
      }
    }
    if (T->p[ip].flags & 1) {
      const float* bias = T->p[ip].bias;
      float bv0 = bias ? bias[colbase + m16] : 0.f;
      float bv1 = bias ? bias[colbase + 16 + m16] : 0.f;
#pragma unroll
      for (int rb = 0; rb < 4; ++rb)
#pragma unroll
        for (int cb = 0; cb < 2; ++cb) {
          float bv = cb ? bv1 : bv0;
#pragma unroll
          for (int r = 0; r < 4; ++r) {
            float v = acc[rb][cb][r] + bv;
            if (T->relu) v = v > 0.f ? v : 0.f;
            accO[rb][cb][r] += v;
          }
          acc[rb][cb] = (ffrag)0.f;
        }
    }
  }
  const int ldc = T->ldc;
#pragma unroll
  for (int rb = 0; rb < 4; ++rb)
#pragma unroll
    for (int cb = 0; cb < 2; ++cb) {
      int col = colbase + cb * 16 + m16;
#pragma unroll
      for (int r = 0; r < 4; ++r) {
        int row = row0 + rb * 16 + kq * 4 + r;
        if (row < n) {
          float v = accO[rb][cb][r];
          if (T->R) v += b2f(T->R[(size_t)row * ldc + col]);
          T->C[(size_t)row * ldc + col] = f2b(v);
        }
      }
    }
}

// MFMA embed from raw flag-dtype A, 32-row tile, BK=64.
// REGISTER DOUBLE-BUFFERED staging (KEPT: measured winner — k_eb dropped out
// of the top-5, 167.7us -> <152.6us); K need not be a multiple of 64.
__device__ void embed_body(const ETask& T, int lx, int bf) {
  const int n = T.n;
  const int row0 = lx * 32;
  if (row0 >= n) return;
  __shared__ __align__(16) unsigned short As[32][72];
  __shared__ __align__(16) unsigned short Ws[128][72];
  const int t = threadIdx.x;
  const int wave = t >> 6, lane = t & 63;
  const int m16 = lane & 15, kq = lane >> 4;
  const int K = T.K;
  const int rbase = t >> 3, col8 = (t & 7) * 8;
  const int arow = row0 + rbase;
  ffrag acc[2][2];
#pragma unroll
  for (int i = 0; i < 2; ++i)
#pragma unroll
    for (int j = 0; j < 2; ++j) acc[i][j] = (ffrag)0.f;
  const int colbase = wave * 32;
  int4 aR; int4 wR[4];
  {  // prefetch k0 = 0
    int k = col8;
    int4 v = {0, 0, 0, 0};
    if (arow < n && k < K) v = ld8(T.A, (size_t)arow * K + k, bf);
    aR = v;
#pragma unroll
    for (int j = 0; j < 4; ++j) {
      int4 w = {0, 0, 0, 0};
      if (k < K) w = *(const int4*)(T.W + (size_t)(rbase + 32 * j) * K + k);
      wR[j] = w;
    }
  }
  for (int k0 = 0; k0 < K; k0 += 64) {
    *(int4*)&As[rbase][col8] = aR;
#pragma unroll
    for (int j = 0; j < 4; ++j) *(int4*)&Ws[rbase + 32 * j][col8] = wR[j];
    if (k0 + 64 < K) {  // issue next step's loads
      int k = k0 + 64 + col8;
      int4 v = {0, 0, 0, 0};
      if (arow < n && k < K) v = ld8(T.A, (size_t)arow * K + k, bf);
      aR = v;
#pragma unroll
      for (int j = 0; j < 4; ++j) {
        int4 w = {0, 0, 0, 0};
        if (k < K) w = *(const int4*)(T.W + (size_t)(rbase + 32 * j) * K + k);
        wR[j] = w;
      }
    }
    __syncthreads();
#pragma unroll
    for (int kk = 0; kk < 64; kk += 32) {
      bfrag a0 = *(const bfrag*)&As[m16][kk + kq * 8];
      bfrag a1 = *(const bfrag*)&As[16 + m16][kk + kq * 8];
      bfrag b0 = *(const bfrag*)&Ws[colbase + m16][kk + kq * 8];
      bfrag b1 = *(const bfrag*)&Ws[colbase + 16 + m16][kk + kq * 8];
      acc[0][0] = __builtin_amdgcn_mfma_f32_16x16x32_bf16(a0, b0, acc[0][0], 0, 0, 0);
      acc[0][1] = __builtin_amdgcn_mfma_f32_16x16x32_bf16(a0, b1, acc[0][1], 0, 0, 0);
      acc[1][0] = __builtin_amdgcn_mfma_f32_16x16x32_bf16(a1, b0, acc[1][0], 0, 0, 0);
      acc[1][1] = __builtin_amdgcn_mfma_f32_16x16x32_bf16(a1, b1, acc[1][1], 0, 0, 0);
    }
    __syncthreads();
  }
#pragma unroll
  for (int rb = 0; rb < 2; ++rb)
#pragma unroll
    for (int cb = 0; cb < 2; ++cb) {
      int col = colbase + cb * 16 + m16;
      float bv = T.bias[col];
#pragma unroll
      for (int r = 0; r < 4; ++r) {
        int row = row0 + rb * 16 + kq * 4 + r;
        if (row < n) {
          float v = acc[rb][cb][r] + bv;
          T.C[(size_t)row * T.ldc + col] = f2b(v > 0.f ? v : 0.f);
        }
      }
    }
}

// ---------------- kernels ----------------

__global__ void k_flag(const unsigned int* probe, int* flag) {
  if (threadIdx.x == 0) *flag = (probe[0] == 0x3F800000u) ? 0 : 1;
}

// CSR pass A: per-chunk LDS histogram; NO global atomics.
__launch_bounds__(256)
__global__ void k_csr_cnt(CsrArgs args, COff co) {
  __shared__ unsigned int h32[10000];  // 40000 B: covers n_dst <= 20000
  int bx = blockIdx.x, l = 0;
  while (l + 1 < NCSR && bx >= co.off[l + 1]) ++l;
  const int b = bx - co.off[l];
  const CsrDesc cd = args.d[l];
  const int nh = (cd.n_dst + 1) >> 1;
  for (int i = threadIdx.x; i < nh; i += 256) h32[i] = 0;
  __syncthreads();
  const int e0 = b << CLOG;
  const int e1 = min(e0 + CCHUNK, cd.E);
  for (int e = e0 + (int)threadIdx.x; e < e1; e += 256) {
    int d = cd.dst[e];
    unsigned int old = atomicAdd(&h32[d >> 1], (d & 1) ? 65536u : 1u);
    cd.slot16[e] = (unsigned short)((d & 1) ? (old >> 16) : (old & 0xFFFFu));
  }
  __syncthreads();
  unsigned int* cb = cd.cnt + (size_t)b * cd.n_dst;
  for (int i = threadIdx.x; i < cd.n_dst; i += 256)
    cb[i] = (i & 1) ? (h32[i >> 1] >> 16) : (h32[i >> 1] & 0xFFFFu);
}

// CSR pass B1: per-dst exclusive prefix over chunk histograms, PARALLEL over
// all (list,dst) pairs.
__launch_bounds__(256)
__global__ void k_csr_chunkpref(CsrArgs args, COff cp, int total) {
  int idx = blockIdx.x * 256 + (int)threadIdx.x;
  if (idx >= total) return;
  int l = 0;
  while (l + 1 < NCSR && idx >= cp.off[l + 1]) ++l;
  const int d = idx - cp.off[l];
  const CsrDesc cd = args.d[l];
  unsigned int s = 0;
  unsigned int* cc = cd.cnt + d;
  const int nb = cd.nb;
  for (int b = 0; b < nb; ++b) {
    unsigned int v = cc[(size_t)b * cd.n_dst];
    cc[(size_t)b * cd.n_dst] = s;
    s += v;
  }
  cd.rowptr[d + 1] = (int)s;
  if (d == 0) cd.rowptr[0] = 0;
}

// CSR pass B2: block-wide inclusive scan of rowptr (one block per list)
__global__ void k_csr_rowscan(CsrArgs args) {
  const CsrDesc cd = args.d[blockIdx.x];
  const int t = threadIdx.x;
  const int n = cd.n_dst + 1;
  const int lane = t & 63, w = t >> 6;
  __shared__ int wsum[16];
  int carry = 0;
  for (int base = 0; base < n; base += 1024) {
    int i = base + t;
    int v = (i < n) ? cd.rowptr[i] : 0;
    for (int off = 1; off < 64; off <<= 1) {
      int u = __shfl_up(v, off, 64);
      if (lane >= off) v += u;
    }
    if (lane == 63) wsum[w] = v;
    __syncthreads();
    if (w == 0) {
      int s = (lane < 16) ? wsum[lane] : 0;
      for (int off = 1; off < 16; off <<= 1) {
        int u = __shfl_up(s, off, 64);
        if (lane >= off) s += u;
      }
      if (lane < 16) wsum[lane] = s;
    }
    __syncthreads();
    int nv = v + carry + (w > 0 ? wsum[w - 1] : 0);
    if (i < n) cd.rowptr[i] = nv;
    carry += wsum[15];
    __syncthreads();
  }
}

// merged embed + biasrelu (no atomics, both MFMA/stream friendly)
__launch_bounds__(256)
__global__ void k_eb(EArgs ea, BArgs ba, const int* __restrict__ flagp) {
  int bx = blockIdx.x;
  if (bx < 1032) {  // embed prefix {0,250,875,1032} for n = 8000/20000/5000, 32-row tiles
    int t, lx;
    if (bx < 250) { t = 0; lx = bx; }
    else if (bx < 875) { t = 1; lx = bx - 250; }
    else { t = 2; lx = bx - 875; }
    embed_body(ea.t[t], lx, *flagp);
    return;
  }
  bx -= 1032;
  bias_body(ba.t[bx >> 7], bx & 127, *flagp);
}

// merged param+weight conversion: [params 21x4][weights 37x32]
__launch_bounds__(256)
__global__ void k_cv(PArgs pa, WArgs wa, const int* __restrict__ flagp) {
  const int bf = *flagp;
  int bx = blockIdx.x;
  if (bx < NPT * 4) {
    const PTask T = pa.t[bx >> 2];
    for (int i = (bx & 3) * 256 + (int)threadIdx.x; i < T.n; i += 4 * 256)
      T.dst[i] = ldf(T.src, (size_t)i, bf);
  } else {
    bx -= NPT * 4;
    const WTask T = wa.t[bx >> 5];
    const int lx = bx & 31;
    const int total = T.K * T.N;
    const size_t eoff = (size_t)T.eoff;
    for (int i = lx * 256 + (int)threadIdx.x; i < total; i += 32 * 256) {
      int n = i / T.K, k = i - n * T.K;
      T.dst[i] = f2b(ldf(T.src, eoff + (size_t)k * T.N + n, bf));
    }
  }
}

// super: [csr_fill 15x96][mg flat]
__launch_bounds__(256)
__global__ void k_fillmg(CsrArgs csr, MSup ms) {
  int bx = blockIdx.x;
  if (bx < NCSR * 96) { fill_body(csr.d[bx / 96], bx % 96); return; }
  bx -= NCSR * 96;
  int lx; int t = find_task(ms.off, ms.nt, bx, lx);
  mg_body(&ms.t[t], lx);
}

// pure gather super (no LDS -> full occupancy)
__global__ void k_gsup(GSup gs) {
  int lx; int t = find_task(gs.off, gs.nt, blockIdx.x, lx);
  gather_body(gs.t[t], lx);
}

// combined gather + mg super
__launch_bounds__(256)
__global__ void k_gm(GSup gs, MSup ms) {
  int bx = blockIdx.x;
  const int gtot = gs.off[gs.nt];
  if (bx < gtot) {
    int lx; int t = find_task(gs.off, gs.nt, bx, lx);
    gather_body(gs.t[t], lx);
    return;
  }
  bx -= gtot;
  int lx; int t = find_task(ms.off, ms.nt, bx, lx);
  mg_body(&ms.t[t], lx);
}

// MFMA GEMM with BN+relu applied to bf16 A while staging; 64-row tile; BK=64
// FUSED per-column sum/sumsq of the pre-bf16 output into st
template<int NC>
__launch_bounds__(256)
__global__ void k_gemm_bn(const unsigned short* __restrict__ A, const unsigned short* __restrict__ W,
                          const float* __restrict__ bias, const float* __restrict__ ss,
                          unsigned short* __restrict__ C, double* __restrict__ st, int n, int K) {
  constexpr int CB = NC / 64;
  __shared__ __align__(16) unsigned short As[64][72];
  __shared__ __align__(16) unsigned short Ws[NC][72];
  const int t = threadIdx.x;
  const int wave = t >> 6, lane = t & 63;
  const int m16 = lane & 15, kq = lane >> 4;
  const int row0 = blockIdx.x * 64;
  if (row0 >= n) return;
  ffrag acc[4][CB];
#pragma unroll
  for (int i = 0; i < 4; ++i)
#pragma unroll
    for (int j = 0; j < CB; ++j) acc[i][j] = (ffrag)0.f;
  const int colbase = wave * 16 * CB;
  for (int k0 = 0; k0 < K; k0 += 64) {
    __syncthreads();
#pragma unroll
    for (int e = t; e < 512; e += 256) {
      int r = e >> 3, c = e & 7;
      int row = row0 + r, k = k0 + c * 8;
      int4 v = {0, 0, 0, 0};
      if (row < n) {
        int4 a8 = *(const int4*)(A + (size_t)row * K + k);
        const unsigned short* pa = (const unsigned short*)&a8;
        unsigned short o[8];
#pragma unroll
        for (int j = 0; j < 8; ++j) {
          float val = fmaf(b2f(pa[j]), ss[k + j], ss[K + k + j]);
          o[j] = f2b(val > 0.f ? val : 0.f);
        }
        v = *(const int4*)o;
      }
      *(int4*)&As[r][c * 8] = v;
    }
#pragma unroll
    for (int e = t; e < NC * 8; e += 256) {
      int nn = e >> 3, c = e & 7;
      *(int4*)&Ws[nn][c * 8] = *(const int4*)(W + (size_t)nn * K + k0 + c * 8);
    }
    __syncthreads();
#pragma unroll
    for (int kk = 0; kk < 64; kk += 32) {
#pragma unroll
      for (int cb = 0; cb < CB; ++cb) {
        bfrag b = *(const bfrag*)&Ws[colbase + cb * 16 + m16][kk + kq * 8];
#pragma unroll
        for (int rb = 0; rb < 4; ++rb) {
          bfrag a = *(const bfrag*)&As[rb * 16 + m16][kk + kq * 8];
          acc[rb][cb] = __builtin_amdgcn_mfma_f32_16x16x32_bf16(a, b, acc[rb][cb], 0, 0, 0);
        }
      }
    }
  }
#pragma unroll
  for (int cb = 0; cb < CB; ++cb) {
    int col = colbase + cb * 16 + m16;
    float bv = bias[col];
    float cs = 0.f, cq = 0.f;
#pragma unroll
    for (int rb = 0; rb < 4; ++rb) {
#pragma unroll
      for (int r = 0; r < 4; ++r) {
        int row = row0 + rb * 16 + kq * 4 + r;
        if (row < n) {
          float v = acc[rb][cb][r] + bv;
          C[(size_t)row * NC + col] = f2b(v);
          cs += v; cq += v * v;
        }
      }
    }
    cs += __shfl_xor(cs, 16); cs += __shfl_xor(cs, 32);
    cq += __shfl_xor(cq, 16); cq += __shfl_xor(cq, 32);
    if (kq == 0) {
      atomicAdd(&st[col], (double)cs);
      atomicAdd(&st[NC + col], (double)cq);
    }
  }
}

// BN1 stats over implicit z1[b] = Udr[x_dr[b]] + Up[x_p[b]]
__global__ void k_hstat(const int* __restrict__ xdr, const int* __restrict__ xp,
                        const unsigned short* __restrict__ Udr, const unsigned short* __restrict__ Up,
                        double* __restrict__ st, int B) {
  __shared__ double sS[4][256];
  __shared__ double sQ[4][256];
  const int t = threadIdx.x;
  const int lane = t & 63, w = t >> 6;
  const int c4 = lane * 4;
  double s0 = 0, s1 = 0, s2 = 0, s3 = 0, q0 = 0, q1 = 0, q2 = 0, q3 = 0;
  const int NW = gridDim.x * 4;
  for (int r = blockIdx.x * 4 + w; r < B; r += NW) {
    int i = xdr[r], j = xp[r];
    uint2 a = *(const uint2*)(Udr + (size_t)i * 256 + c4);
    uint2 b = *(const uint2*)(Up + (size_t)j * 256 + c4);
    float v0 = b2f((unsigned short)a.x) + b2f((unsigned short)b.x);
    float v1 = b2f((unsigned short)(a.x >> 16)) + b2f((unsigned short)(b.x >> 16));
    float v2 = b2f((unsigned short)a.y) + b2f((unsigned short)b.y);
    float v3 = b2f((unsigned short)(a.y >> 16)) + b2f((unsigned short)(b.y >> 16));
    s0 += v0; s1 += v1; s2 += v2; s3 += v3;
    q0 += (double)v0 * (double)v0; q1 += (double)v1 * (double)v1;
    q2 += (double)v2 * (double)v2; q3 += (double)v3 * (double)v3;
  }
  sS[w][c4] = s0; sS[w][c4 + 1] = s1; sS[w][c4 + 2] = s2; sS[w][c4 + 3] = s3;
  sQ[w][c4] = q0; sQ[w][c4 + 1] = q1; sQ[w][c4 + 2] = q2; sQ[w][c4 + 3] = q3;
  __syncthreads();
  double ts = sS[0][t] + sS[1][t] + sS[2][t] + sS[3][t];
  double tq = sQ[0][t] + sQ[1][t] + sQ[2][t] + sQ[3][t];
  atomicAdd(&st[t], ts);
  atomicAdd(&st[256 + t], tq);
}

// MLP layer 2: A gathered on the fly, BN1+relu inline; BK=64; fused col stats
__launch_bounds__(256)
__global__ void k_gemm_bn1(const int* __restrict__ xdr, const int* __restrict__ xp,
                           const unsigned short* __restrict__ Udr, const unsigned short* __restrict__ Up,
                           const unsigned short* __restrict__ W, const float* __restrict__ bias,
                           const float* __restrict__ ss, unsigned short* __restrict__ Co,
                           double* __restrict__ st, int n) {
  __shared__ __align__(16) unsigned short As[64][72];
  __shared__ __align__(16) unsigned short Ws[128][72];
  __shared__ int gi[64], gj[64];
  const int t = threadIdx.x;
  const int wave = t >> 6, lane = t & 63;
  const int m16 = lane & 15, kq = lane >> 4;
  const int row0 = blockIdx.x * 64;
  if (row0 >= n) return;
  if (t < 64) {
    int row = row0 + t; if (row >= n) row = n - 1;
    gi[t] = xdr[row]; gj[t] = xp[row];
  }
  ffrag acc[4][2];
#pragma unroll
  for (int i = 0; i < 4; ++i)
#pragma unroll
    for (int j = 0; j < 2; ++j) acc[i][j] = (ffrag)0.f;
  const int colbase = wave * 32;
  __syncthreads();
  for (int k0 = 0; k0 < 256; k0 += 64) {
    __syncthreads();
#pragma unroll
    for (int e = t; e < 512; e += 256) {
      int r = e >> 3, seg = e & 7;
      int k = k0 + seg * 8;
      int4 a = *(const int4*)(Udr + (size_t)gi[r] * 256 + k);
      int4 b = *(const int4*)(Up + (size_t)gj[r] * 256 + k);
      const unsigned short* pa = (const unsigned short*)&a;
      const unsigned short* pb = (const unsigned short*)&b;
      unsigned short o[8];
#pragma unroll
      for (int jj = 0; jj < 8; ++jj) {
        float v = b2f(pa[jj]) + b2f(pb[jj]);
        v = fmaf(v, ss[k + jj], ss[256 + k + jj]);
        o[jj] = f2b(v > 0.f ? v : 0.f);
      }
      *(int4*)&As[r][seg * 8] = *(const int4*)o;
    }
#pragma unroll
    for (int e = t; e < 1024; e += 256) {
      int nn = e >> 3, c = e & 7;
      *(int4*)&Ws[nn][c * 8] = *(const int4*)(W + (size_t)nn * 256 + k0 + c * 8);
    }
    __syncthreads();
#pragma unroll
    for (int kk = 0; kk < 64; kk += 32) {
      bfrag b0 = *(const bfrag*)&Ws[colbase + m16][kk + kq * 8];
      bfrag b1 = *(const bfrag*)&Ws[colbase + 16 + m16][kk + kq * 8];
#pragma unroll
      for (int rb = 0; rb < 4; ++rb) {
        bfrag a = *(const bfrag*)&As[rb * 16 + m16][kk + kq * 8];
        acc[rb][0] = __builtin_amdgcn_mfma_f32_16x16x32_bf16(a, b0, acc[rb][0], 0, 0, 0);
        acc[rb][1] = __builtin_amdgcn_mfma_f32_16x16x32_bf16(a, b1, acc[rb][1], 0, 0, 0);
      }
    }
  }
#pragma unroll
  for (int cb = 0; cb < 2; ++cb) {
    int col = colbase + cb * 16 + m16;
    float bv = bias[col];
    float cs = 0.f, cq = 0.f;
#pragma unroll
    for (int rb = 0; rb < 4; ++rb) {
#pragma unroll
      for (int r = 0; r < 4; ++r) {
        int row = row0 + rb * 16 + kq * 4 + r;
        if (row < n) {
          float v = acc[rb][cb][r] + bv;
          Co[(size_t)row * 128 + col] = f2b(v);
          cs += v; cq += v * v;
        }
      }
    }
    cs += __shfl_xor(cs, 16); cs += __shfl_xor(cs, 32);
    cq += __shfl_xor(cq, 16); cq += __shfl_xor(cq, 32);
    if (kq == 0) {
      atomicAdd(&st[col], (double)cs);
      atomicAdd(&st[128 + col], (double)cq);
    }
  }
}

__global__ void k_bnfin(const double* __restrict__ st, int B, int C,
                        const float* __restrict__ g, const float* __restrict__ be,
                        float* __restrict__ ss) {
  int c = threadIdx.x;
  if (c < C) {
    double m = st[c] / B;
    double v = st[C + c] / B - m * m;
    if (v < 0) v = 0;
    float sc = (float)((double)g[c] / sqrt(v + 1e-5));
    ss[c] = sc;
    ss[C + c] = be[c] - (float)m * sc;
  }
}

__global__ void k_final(const unsigned short* __restrict__ Z3, const float* __restrict__ ss3,
                        const float* __restrict__ Wo, const float* __restrict__ bo,
                        void* __restrict__ out, int B, const int* __restrict__ flagp) {
  __shared__ float w[64], sc[64], sh[64];
  if (threadIdx.x < 64) {
    w[threadIdx.x] = Wo[threadIdx.x];
    sc[threadIdx.x] = ss3[threadIdx.x];
    sh[threadIdx.x] = ss3[64 + threadIdx.x];
  }
  __syncthreads();
  const int bf = *flagp;
  const float bb = bo[0];
  for (int r = blockIdx.x * blockDim.x + threadIdx.x; r < B; r += gridDim.x * blockDim.x) {
    const unsigned short* z = &Z3[(size_t)r * 64];
    float acc = bb;
#pragma unroll
    for (int k = 0; k < 64; ++k) {
      float y = fmaf(b2f(z[k]), sc[k], sh[k]);
      y = y > 0.f ? y : 0.f;
      acc = fmaf(y, w[k], acc);
    }
    float sv = 1.f / (1.f + expf(-acc));
    if (bf) ((unsigned short*)out)[r] = f2b(sv);
    else ((float*)out)[r] = sv;
  }
}

extern "C" void kernel_launch(void* const* d_in, const int* in_sizes, int n_in,
                              void* d_out, int out_size, void* d_ws, size_t ws_size,
                              hipStream_t stream) {
  enum { N_DR = 8000, N_P = 20000, N_DIS = 5000, N_MF = 3000, N_BP = 8000,
         N_CC = 2000, N_PATH = 2392 };
  if (n_in < 59) return;
  const int B = in_sizes[0];
  const int* x_dr = (const int*)d_in[0];
  const int* x_p  = (const int*)d_in[1];

  char* base = (char*)d_ws;
  size_t off = 0;
  auto alloc = [&](size_t bytes) -> void* {
    void* p = base + off;
    off += (bytes + 255) & ~(size_t)255;
    return p;
  };
  int*    flagp = (int*)alloc(256);
  double* st1 = (double*)alloc(896 * sizeof(double));
  double* st2 = st1 + 512; double* st3 = st2 + 256;
  float*  ss1 = (float*)alloc(896 * sizeof(float));
  float*  ss2 = ss1 + 512; float* ss3 = ss2 + 256;
  float*  pbuf = (float*)alloc(6000 * sizeof(float));
  unsigned short* wbf = (unsigned short*)alloc(1100000 * 2);
  unsigned short* DR  = (unsigned short*)alloc((size_t)N_DR * 384 * 2);
  unsigned short* P   = (unsigned short*)alloc((size_t)N_P * 512 * 2);
  unsigned short* h_d = (unsigned short*)alloc((size_t)N_DIS * 128 * 2);
  unsigned short* d1b = (unsigned short*)alloc((size_t)N_DIS * 128 * 2);
  unsigned short* z1  = (unsigned short*)alloc((size_t)B * 256 * 2);
  char* arena = (char*)alloc(46u * 1024 * 1024);
  if (off > ws_size) return;

  // ---- arena layout (ushort units) ----
  unsigned short* ar = (unsigned short*)arena;
  unsigned short* A_hmf  = ar;
  unsigned short* A_hbp  = A_hmf + (size_t)N_MF * 128;
  unsigned short* A_hcc  = A_hbp + (size_t)N_BP * 128;
  unsigned short* A_hpath= A_hcc + (size_t)N_CC * 128;
  unsigned short* A_gomf = A_hpath + (size_t)N_PATH * 128;
  unsigned short* A_gobp = A_gomf + (size_t)N_MF * 128;
  unsigned short* A_gocc = A_gobp + (size_t)N_BP * 128;
  unsigned short* ag17 = A_gocc + (size_t)N_CC * 128;
  unsigned short* ag18 = ag17 + (size_t)N_MF * 128;
  unsigned short* ag9  = ag18 + (size_t)N_BP * 128;
  unsigned short* ag10 = ag9  + (size_t)N_DR * 128;
  unsigned short* ag11 = ag10 + (size_t)N_DR * 128;
  unsigned short* ag12 = ag11 + (size_t)N_P * 128;
  unsigned short* ag13 = ag12 + (size_t)N_DIS * 128;
  unsigned short* ag14 = ag13 + (size_t)N_DIS * 128;
  unsigned short* ag15 = ag14 + (size_t)N_DIS * 128;
  unsigned short* ag16 = ag15 + (size_t)N_DR * 128;
  unsigned short* ag21 = ag16 + (size_t)N_P * 128;
  unsigned short* ag22 = ag21 + (size_t)N_P * 128;
  unsigned short* ag23 = ag22 + (size_t)N_P * 128;
  unsigned short* U_dr = ar;
  unsigned short* U_p  = U_dr + (size_t)N_DR * 256;
  unsigned short* z2 = U_p + (size_t)N_P * 256;
  unsigned short* z3 = z1;
  // CSR scratch (slot16 + cnt) at arena elems 7.168M+ (z2 region): written by
  // cnt/chunkpref, read by fill; dead before ag11+ writes at L5 and z2 at bn1.
  unsigned short* slot_base = ar + (size_t)7168000;

  // L0: CSR pass A (depends only on edge inputs)
  const int list_ei[NCSR] = {9, 10, 11, 12, 13, 14, 15, 16, 17, 18, 19, 20, 21, 22, 23};
  const int list_nd[NCSR] = {N_DR, N_DR, N_P, N_DIS, N_DIS, N_DIS, N_DR, N_P,
                             N_MF, N_BP, N_CC, N_P, N_P, N_P, N_P};
  int* rp[24]; unsigned short* cs[24];
  CsrArgs csra;
  COff coff, cpref;
  unsigned short* csr_end;
  {
    // rowptr + csrc live in z1 head
    int* ip = (int*)z1;
    for (int l = 0; l < NCSR; ++l) { csra.d[l].rowptr = ip; rp[list_ei[l]] = ip; ip += list_nd[l] + 1; }
    unsigned short* up = (unsigned short*)ip;
    unsigned short* sp = slot_base;
    for (int l = 0; l < NCSR; ++l) {
      int ei = list_ei[l];
      int E = in_sizes[ei] / 2;
      csra.d[l].src = (const int*)d_in[ei];
      csra.d[l].dst = (const int*)d_in[ei] + E;
      csra.d[l].E = E;
      csra.d[l].n_dst = list_nd[l];
      csra.d[l].nb = (E + CCHUNK - 1) >> CLOG;
      csra.d[l].csrc = up; cs[ei] = up;
      csra.d[l].slot16 = sp;
      up += E;
      sp += E;
    }
    csr_end = up;
    unsigned int* cp = (unsigned int*)(((uintptr_t)sp + 255) & ~(uintptr_t)255);
    coff.off[0] = 0;
    cpref.off[0] = 0;
    for (int l = 0; l < NCSR; ++l) {
      csra.d[l].cnt = cp;
      cp += (size_t)csra.d[l].nb * csra.d[l].n_dst;
      coff.off[l + 1] = coff.off[l] + csra.d[l].nb;
      cpref.off[l + 1] = cpref.off[l] + csra.d[l].n_dst;
    }
  }
  k_csr_cnt<<<coff.off[NCSR], 256, 0, stream>>>(csra, coff);

  k_flag<<<1, 64, 0, stream>>>((const unsigned int*)d_in[5], flagp);

  // ---- L1: merged conversions ----
  float* pp[59] = {};
  PArgs pa;
  {
    const int pidx[NPT] = {25,27,29,31,33,35,37,39,41,44,46,47,48,50,51,52,54,55,56,57,58};
    size_t poff = 0;
    for (int l = 0; l < NPT; ++l) {
      int i = pidx[l];
      pa.t[l].src = d_in[i]; pa.t[l].dst = pbuf + poff; pa.t[l].n = in_sizes[i]; pa.t[l].pad = 0;
      pp[i] = pbuf + poff;
      poff += in_sizes[i];
    }
  }
  unsigned short *Wdr_t, *Wpe_t, *Wde_t, *Wg_t, *Wps_t, *Wss_t, *Wns_t, *W1_t, *W2_t, *W3_t;
  WArgs wa;
  {
    int l = 0; size_t woff = 0;
    auto add = [&](int inIdx, int eoff, int K, int N) -> unsigned short* {
      unsigned short* dst = wbf + woff;
      wa.t[l].src = d_in[inIdx]; wa.t[l].dst = dst; wa.t[l].K = K; wa.t[l].N = N;
      wa.t[l].eoff = eoff; wa.t[l].pad = 0;
      ++l; woff += (size_t)K * N;
      return dst;
    };
    Wdr_t = add(24, 0, 1024, 128);
    Wpe_t = add(26, 0, 400, 128);
    Wde_t = add(28, 0, 512, 128);
    Wg_t = wbf + woff;
    for (int j = 0; j < 7; ++j) add(38, j * 16384, 128, 128);
    Wps_t = wbf + woff;
    for (int j = 0; j < 8; ++j) add(40, j * 16384, 128, 128);
    Wss_t = wbf + woff;
    for (int j = 0; j < 8; ++j) add(42, j * 16384, 128, 128);
    Wns_t = wbf + woff;
    for (int j = 0; j < 8; ++j) add(43, j * 16384, 128, 128);
    W1_t = add(45, 0, 896, 256);
    W2_t = add(49, 0, 256, 128);
    W3_t = add(53, 0, 128, 64);
  }
  k_cv<<<NPT * 4 + NWT * 32, 256, 0, stream>>>(pa, wa, flagp);

  // pl0-7, ag19, ag20 in z1 after CSR content
  unsigned short* plb = (unsigned short*)(((uintptr_t)csr_end + 255) & ~(uintptr_t)255);
  unsigned short* plz0 = plb;
  unsigned short* plz1 = plz0 + (size_t)N_DIS * 128;
  unsigned short* plz2 = plz1 + (size_t)N_DIS * 128;
  unsigned short* plz3 = plz2 + (size_t)N_DIS * 128;
  unsigned short* plz4 = plz3 + (size_t)N_DR * 128;
  unsigned short* plz5 = plz4 + (size_t)N_DR * 128;
  unsigned short* plz6 = plz5 + (size_t)N_P * 128;
  unsigned short* plz7 = plz6 + (size_t)N_DR * 128;
  unsigned short* ag19 = plz7 + (size_t)N_P * 128;
  unsigned short* ag20 = ag19 + (size_t)N_CC * 128;
  if ((ag20 + (size_t)N_P * 128) > (z1 + (size_t)B * 256)) return;  // capacity guard

  hipMemsetAsync(st1, 0, 896 * sizeof(double), stream);

  auto mkpass = [](MTask& T, int i, const unsigned short* A, int lda, const unsigned short* W,
                   int ldw, const float* bias, int end) {
    T.p[i].A = A; T.p[i].lda = lda; T.p[i].W = W; T.p[i].ldw = ldw;
    T.p[i].bias = bias; T.p[i].flags = end;
  };
  const float* bg = pp[39];
  const float* bp_s = pp[41];
  const float* b_s = pp[44];

  auto gadd = [](GSup& g, GTask t) {
    if (g.nt == 0) g.off[0] = 0;
    g.t[g.nt] = t;
    g.off[g.nt + 1] = g.off[g.nt] + (t.n_dst + 3) / 4;
    g.nt++;
  };
  auto madd = [](MSup& m, const MTask& t) {
    if (m.nt == 0) m.off[0] = 0;
    m.t[m.nt] = t;
    m.off[m.nt + 1] = m.off[m.nt] + (t.n + 63) / 64;
    m.nt++;
  };

  // ---- L2: embed + biasrelu (atomic-free) ----
  {
    EArgs ea;
    ea.t[0] = {d_in[2], Wdr_t, pp[25], DR, N_DR, 1024, 384, 0};
    ea.t[1] = {d_in[3], Wpe_t, pp[27], P, N_P, 400, 512, 0};
    ea.t[2] = {d_in[4], Wde_t, pp[29], h_d, N_DIS, 512, 128, 0};
    BArgs ba;
    ba.t[0] = {d_in[30], pp[31], A_hmf, N_MF * 128, {}};
    ba.t[1] = {d_in[32], pp[33], A_hbp, N_BP * 128, {}};
    ba.t[2] = {d_in[34], pp[35], A_hcc, N_CC * 128, {}};
    ba.t[3] = {d_in[36], pp[37], A_hpath, N_PATH * 128, {}};
    k_eb<<<1032 + 4 * 128, 256, 0, stream>>>(ea, ba, flagp);
  }

  // ---- L3: CSR pass B (parallel chunk-prefix, then per-list row scan) ----
  k_csr_chunkpref<<<(cpref.off[NCSR] + 255) / 256, 256, 0, stream>>>(csra, cpref, cpref.off[NCSR]);
  k_csr_rowscan<<<NCSR, 1024, 0, stream>>>(csra);

  // ---- L4: csr_fill || SAGE-pool-8 GEMM (pl* -> z1) ----
  {
    MSup ms; ms.nt = 0;
    const unsigned short* xs[8] = {h_d, h_d, h_d, DR, DR, P, DR, P};
    const int lda[8] = {128, 128, 128, 384, 384, 512, 384, 512};
    const int nn[8] = {N_DIS, N_DIS, N_DIS, N_DR, N_DR, N_P, N_DR, N_P};
    unsigned short* plo[8] = {plz0, plz1, plz2, plz3, plz4, plz5, plz6, plz7};
    for (int i = 0; i < 8; ++i) {
      MTask T;
      mkpass(T, 0, xs[i], lda[i], Wps_t + (size_t)i * 16384, 128, bp_s + i * 128, 1);
      T.npass = 1; T.n = nn[i]; T.K = 128; T.R = nullptr; T.C = plo[i]; T.ldc = 128; T.relu = 1;
      madd(ms, T);
    }
    k_fillmg<<<NCSR * 96 + ms.off[ms.nt], 256, 0, stream>>>(csra, ms);
  }

  // ---- L5: all first-round gathers (GO sims + SAGE pool) ----
  {
    GSup gs; gs.nt = 0;
    gadd(gs, {rp[17], cs[17], A_hmf, ag17, N_MF, 128, 0, 0});
    gadd(gs, {rp[18], cs[18], A_hbp, ag18, N_BP, 128, 0, 0});
    gadd(gs, {rp[19], cs[19], A_hcc, ag19, N_CC, 128, 0, 0});
    gadd(gs, {rp[9],  cs[9],  plz0, ag9,  N_DR, 128, 1, 0});
    gadd(gs, {rp[10], cs[10], plz1, ag10, N_DR, 128, 1, 0});
    gadd(gs, {rp[11], cs[11], plz2, ag11, N_P, 128, 1, 0});
    gadd(gs, {rp[12], cs[12], plz3, ag12, N_DIS, 128, 1, 0});
    gadd(gs, {rp[13], cs[13], plz4, ag13, N_DIS, 128, 1, 0});
    gadd(gs, {rp[14], cs[14], plz5, ag14, N_DIS, 128, 1, 0});
    gadd(gs, {rp[15], cs[15], plz6, ag15, N_DR, 128, 1, 0});
    gadd(gs, {rp[16], cs[16], plz7, ag16, N_P, 128, 1, 0});
    k_gsup<<<gs.off[gs.nt], 256, 0, stream>>>(gs);
  }

  GSup g0; g0.nt = 0; g0.off[0] = 0;  // empty gather section for pure-mg launches

  // ---- L6: GO-GCN (3) || hetero-combine-1 (3) ----
  {
    MSup ms; ms.nt = 0;
    for (int i = 0; i < 3; ++i) {
      MTask T;
      const unsigned short* aggp = (i == 0) ? ag17 : (i == 1) ? ag18 : ag19;
      const unsigned short* Rp = (i == 0) ? A_hmf : (i == 1) ? A_hbp : A_hcc;
      unsigned short* Cp = (i == 0) ? A_gomf : (i == 1) ? A_gobp : A_gocc;
      int n = (i == 0) ? N_MF : (i == 1) ? N_BP : N_CC;
      mkpass(T, 0, aggp, 128, Wg_t + (size_t)i * 16384, 128, bg + i * 128, 1);
      T.npass = 1; T.n = n; T.K = 128; T.R = Rp; T.C = Cp; T.ldc = 128; T.relu = 1;
      madd(ms, T);
    }
    {
      MTask T;
      mkpass(T, 0, DR, 384, Wss_t + (size_t)0 * 16384, 128, nullptr, 0);
      mkpass(T, 1, ag9, 128, Wns_t + (size_t)0 * 16384, 128, b_s + 0 * 128, 1);
      mkpass(T, 2, DR, 384, Wss_t + (size_t)1 * 16384, 128, nullptr, 0);
      mkpass(T, 3, ag10, 128, Wns_t + (size_t)1 * 16384, 128, b_s + 1 * 128, 1);
      mkpass(T, 4, DR, 384, Wss_t + (size_t)6 * 16384, 128, nullptr, 0);
      mkpass(T, 5, ag15, 128, Wns_t + (size_t)6 * 16384, 128, b_s + 6 * 128, 1);
      T.npass = 6; T.n = N_DR; T.K = 128; T.R = nullptr; T.C = DR + 128; T.ldc = 384; T.relu = 1;
      madd(ms, T);
    }
    {
      MTask T;
      mkpass(T, 0, P, 512, Wss_t + (size_t)2 * 16384, 128, nullptr, 0);
      mkpass(T, 1, ag11, 128, Wns_t + (size_t)2 * 16384, 128, b_s + 2 * 128, 1);
      mkpass(T, 2, P, 512, Wss_t + (size_t)7 * 16384, 128, nullptr, 0);
      mkpass(T, 3, ag16, 128, Wns_t + (size_t)7 * 16384, 128, b_s + 7 * 128, 1);
      T.npass = 4; T.n = N_P; T.K = 128; T.R = nullptr; T.C = P + 128; T.ldc = 512; T.relu = 1;
      madd(ms, T);
    }
    {
      MTask T;
      mkpass(T, 0, h_d, 128, Wss_t + (size_t)3 * 16384, 128, nullptr, 0);
      mkpass(T, 1, ag12, 128, Wns_t + (size_t)3 * 16384, 128, b_s + 3 * 128, 1);
      mkpass(T, 2, h_d, 128, Wss_t + (size_t)4 * 16384, 128, nullptr, 0);
      mkpass(T, 3, ag13, 128, Wns_t + (size_t)4 * 16384, 128, b_s + 4 * 128, 1);
      mkpass(T, 4, h_d, 128, Wss_t + (size_t)5 * 16384, 128, nullptr, 0);
      mkpass(T, 5, ag14, 128, Wns_t + (size_t)5 * 16384, 128, b_s + 5 * 128, 1);
      T.npass = 6; T.n = N_DIS; T.K = 128; T.R = nullptr; T.C = d1b; T.ldc = 128; T.relu = 1;
      madd(ms, T);
    }
    k_gm<<<ms.off[ms.nt], 256, 0, stream>>>(g0, ms);
  }

  // ---- L7: GO->P gathers (4) || SAGE-pool-2 (5) ----
  {
    GSup gs; gs.nt = 0;
    gadd(gs, {rp[20], cs[20], A_gomf, ag20, N_P, 128, 0, 0});
    gadd(gs, {rp[21], cs[21], A_gobp, ag21, N_P, 128, 0, 0});
    gadd(gs, {rp[22], cs[22], A_gocc, ag22, N_P, 128, 0, 0});
    gadd(gs, {rp[23], cs[23], A_hpath, ag23, N_P, 128, 0, 0});
    MSup ms; ms.nt = 0;
    const unsigned short* xs[5] = {d1b, d1b, d1b, DR + 128, P + 128};
    const int lda[5] = {128, 128, 128, 384, 512};
    const int nn[5] = {N_DIS, N_DIS, N_DIS, N_DR, N_P};
    unsigned short* plo[5] = {plz0, plz1, plz2, plz6, plz7};
    const int si[5] = {0, 1, 2, 6, 7};
    for (int i = 0; i < 5; ++i) {
      MTask T;
      mkpass(T, 0, xs[i], lda[i], Wps_t + (size_t)si[i] * 16384, 128, bp_s + si[i] * 128, 1);
      T.npass = 1; T.n = nn[i]; T.K = 128; T.R = nullptr; T.C = plo[i]; T.ldc = 128; T.relu = 1;
      madd(ms, T);
    }
    k_gm<<<gs.off[gs.nt] + ms.off[ms.nt], 256, 0, stream>>>(gs, ms);
  }

  // ---- L8: GO->P GEMM (1) || second-round gathers (5) ----
  {
    GSup gs; gs.nt = 0;
    gadd(gs, {rp[9],  cs[9],  plz0, ag9,  N_DR, 128, 1, 0});
    gadd(gs, {rp[10], cs[10], plz1, ag10, N_DR, 128, 1, 0});
    gadd(gs, {rp[11], cs[11], plz2, ag11, N_P, 128, 1, 0});
    gadd(gs, {rp[15], cs[15], plz6, ag15, N_DR, 128, 1, 0});
    gadd(gs, {rp[16], cs[16], plz7, ag16, N_P, 128, 1, 0});
    MSup ms; ms.nt = 0;
    MTask T;
    mkpass(T, 0, ag20, 128, Wg_t + 3 * 16384, 128, bg + 3 * 128, 1);
    mkpass(T, 1, ag21, 128, Wg_t + 4 * 16384, 128, bg + 4 * 128, 1);
    mkpass(T, 2, ag22, 128, Wg_t + 5 * 16384, 128, bg + 5 * 128, 1);
    mkpass(T, 3, ag23, 128, Wg_t + 6 * 16384, 128, bg + 6 * 128, 1);
    T.npass = 4; T.n = N_P; T.K = 128; T.R = nullptr; T.C = P + 384; T.ldc = 512; T.relu = 1;
    madd(ms, T);
    k_gm<<<gs.off[gs.nt] + ms.off[ms.nt], 256, 0, stream>>>(gs, ms);
  }

  // ---- L9: hetero-combine-2 (2) ----
  {
    MSup ms; ms.nt = 0;
    {
      MTask T;
      mkpass(T, 0, DR + 128, 384, Wss_t + (size_t)0 * 16384, 128, nullptr, 0);
      mkpass(T, 1, ag9, 128, Wns_t + (size_t)0 * 16384, 128, b_s + 0 * 128, 1);
      mkpass(T, 2, DR + 128, 384, Wss_t + (size_t)1 * 16384, 128, nullptr, 0);
      mkpass(T, 3, ag10, 128, Wns_t + (size_t)1 * 16384, 128, b_s + 1 * 128, 1);
      mkpass(T, 4, DR + 128, 384, Wss_t + (size_t)6 * 16384, 128, nullptr, 0);
      mkpass(T, 5, ag15, 128, Wns_t + (size_t)6 * 16384, 128, b_s + 6 * 128, 1);
      T.npass = 6; T.n = N_DR; T.K = 128; T.R = nullptr; T.C = DR + 256; T.ldc = 384; T.relu = 1;
      madd(ms, T);
    }
    {
      MTask T;
      mkpass(T, 0, P + 128, 512, Wss_t + (size_t)2 * 16384, 128, nullptr, 0);
      mkpass(T, 1, ag11, 128, Wns_t + (size_t)2 * 16384, 128, b_s + 2 * 128, 1);
      mkpass(T, 2, P + 128, 512, Wss_t + (size_t)7 * 16384, 128, nullptr, 0);
      mkpass(T, 3, ag16, 128, Wns_t + (size_t)7 * 16384, 128, b_s + 7 * 128, 1);
      T.npass = 4; T.n = N_P; T.K = 128; T.R = nullptr; T.C = P + 256; T.ldc = 512; T.relu = 1;
      madd(ms, T);
    }
    k_gm<<<ms.off[ms.nt], 256, 0, stream>>>(g0, ms);
  }

  // ---- L10: W1 GEMM (4) ----
  {
    MSup ms; ms.nt = 0;
    for (int half = 0; half < 2; ++half) {
      {
        MTask T;
        mkpass(T, 0, DR, 384, W1_t + (size_t)(half * 128) * 896, 896, pp[46] + half * 128, 1);
        T.npass = 1; T.n = N_DR; T.K = 384; T.R = nullptr;
        T.C = U_dr + half * 128; T.ldc = 256; T.relu = 0;
        madd(ms, T);
      }
      {
        MTask T;
        mkpass(T, 0, P, 512, W1_t + (size_t)(half * 128) * 896 + 384, 896, nullptr, 1);
        T.npass = 1; T.n = N_P; T.K = 512; T.R = nullptr;
        T.C = U_p + half * 128; T.ldc = 256; T.relu = 0;
        madd(ms, T);
      }
    }
    k_gm<<<ms.off[ms.nt], 256, 0, stream>>>(g0, ms);
  }

  // ---- MLP tail ----
  k_hstat<<<256, 256, 0, stream>>>(x_dr, x_p, U_dr, U_p, st1, B);
  k_bnfin<<<1, 256, 0, stream>>>(st1, B, 256, pp[47], pp[48], ss1);

  k_gemm_bn1<<<(B + 63) / 64, 256, 0, stream>>>(x_dr, x_p, U_dr, U_p, W2_t, pp[50], ss1, z2, st2, B);
  k_bnfin<<<1, 128, 0, stream>>>(st2, B, 128, pp[51], pp[52], ss2);

  k_gemm_bn<64><<<(B + 63) / 64, 256, 0, stream>>>(z2, W3_t, pp[54], ss2, z3, st3, B, 128);
  k_bnfin<<<1, 64, 0, stream>>>(st3, B, 64, pp[55], pp[56], ss3);

  k_final<<<256, 256, 0, stream>>>(z3, ss3, pp[57], pp[58], d_out, B, flagp);
}